// Round 1
// baseline (541.868 us; speedup 1.0000x reference)
//
#include <hip/hip_runtime.h>
#include <hip/hip_bf16.h>

#define DEPTHL 2
#define DIMM   512
#define NHEADS 8
#define DHH    64
#define INNERD 512
#define MLPD   2048
#define BB     2
#define SEQL   2048
#define ROWS   (BB*SEQL)
#define NEGF   (-3.402823466e38f)
#define SCALEF 0.125f

typedef __attribute__((ext_vector_type(4))) float f32x4;
typedef __attribute__((ext_vector_type(8))) __bf16 bf16x8;

#define GLDS16(g, l) __builtin_amdgcn_global_load_lds((const __attribute__((address_space(1))) void*)(g), (__attribute__((address_space(3))) void*)(l), 16, 0, 0)

__device__ __forceinline__ unsigned short f2bf(float f) {
  union { float f; unsigned int u; } v; v.f = f;
  unsigned int r = v.u + 0x7fffu + ((v.u >> 16) & 1u);
  return (unsigned short)(r >> 16);
}

// ---------------- weight transpose fp32[K][N] -> bf16[N][K] ----------------
__global__ __launch_bounds__(256) void wtrans(const float* __restrict__ wsrc,
                                              unsigned short* __restrict__ wdst,
                                              int K, int N) {
  __shared__ float t[32][33];
  const float* src = wsrc + (size_t)blockIdx.z * K * N;
  unsigned short* dst = wdst + (size_t)blockIdx.z * K * N;
  int k0 = blockIdx.x * 32, n0 = blockIdx.y * 32;
  int tx = threadIdx.x & 31, ty = threadIdx.x >> 5;  // 32x8
#pragma unroll
  for (int j = 0; j < 32; j += 8)
    t[ty + j][tx] = src[(size_t)(k0 + ty + j) * N + n0 + tx];
  __syncthreads();
#pragma unroll
  for (int j = 0; j < 32; j += 8)
    dst[(size_t)(n0 + ty + j) * K + k0 + tx] = f2bf(t[tx][ty + j]);
}

// ---------------- adain ----------------
__global__ __launch_bounds__(512) void adain_p1(const float* __restrict__ x,
                                                float* __restrict__ p1, float* __restrict__ p2) {
  int d = threadIdx.x, c = blockIdx.x, b = blockIdx.y;
  const float* xp = x + ((size_t)b * SEQL + c * 64) * DIMM + d;
  float s = 0.f, s2 = 0.f;
  for (int i = 0; i < 64; ++i) { float v = xp[(size_t)i * DIMM]; s += v; s2 += v * v; }
  p1[(b * 32 + c) * DIMM + d] = s;
  p2[(b * 32 + c) * DIMM + d] = s2;
}

__global__ __launch_bounds__(512) void adain_p2(const float* __restrict__ p1, const float* __restrict__ p2,
                                                const float* __restrict__ w, const float* __restrict__ bi,
                                                float* __restrict__ alpha, float* __restrict__ beta) {
  int d = threadIdx.x, b = blockIdx.x;
  float s = 0.f, s2 = 0.f;
  for (int c = 0; c < 32; ++c) { s += p1[(b * 32 + c) * DIMM + d]; s2 += p2[(b * 32 + c) * DIMM + d]; }
  float mean = s * (1.0f / SEQL);
  float var = s2 * (1.0f / SEQL) - mean * mean;
  float a = w[b * DIMM + d] * rsqrtf(var + 1e-6f);
  alpha[b * DIMM + d] = a;
  beta[b * DIMM + d] = bi[b * DIMM + d] - mean * a;
}

__global__ __launch_bounds__(256) void adain_apply(const float* __restrict__ x,
                                                   const float* __restrict__ alpha, const float* __restrict__ beta,
                                                   unsigned short* __restrict__ hb) {
  int idx = blockIdx.x * 256 + threadIdx.x;  // over ROWS*DIMM = 2^21
  int d = idx & (DIMM - 1);
  int b = idx >> 20;  // SEQL*DIMM = 2^20
  hb[idx] = f2bf(x[idx] * alpha[b * DIMM + d] + beta[b * DIMM + d]);
}

// ---------------- GEMM: out = A[M,K](bf16) @ Wt[N,K]^T(bf16) (+bias)(+gelu)(+resid) ----------------
// EPI: 0 = bf16 out (no bias unless given), 1 = gelu -> bf16 out, 2 = fp32 out + resid
template <int EPI>
__global__ __launch_bounds__(256)
void gemm_k(const unsigned short* __restrict__ A,
            const unsigned short* __restrict__ Wt,
            const float* __restrict__ bias,
            const float* __restrict__ resid,
            float* __restrict__ outF,
            unsigned short* __restrict__ outB,
            int N, int K) {
  __shared__ __align__(16) unsigned short As[128 * 32];
  __shared__ __align__(16) unsigned short Bs[128 * 32];
  const int tid = threadIdx.x;
  const int w = tid >> 6, lane = tid & 63;
  const int bm = blockIdx.y * 128, bn = blockIdx.x * 128;
  const int wm = (w >> 1) * 64, wn = (w & 1) * 64;

  f32x4 acc[4][4] = {};

  const int sr0 = w * 32 + (lane >> 2);
  const int sc = lane & 3;

  for (int k0 = 0; k0 < K; k0 += 32) {
#pragma unroll
    for (int j = 0; j < 2; ++j) {
      int r = sr0 + j * 16;
      int cl = sc ^ ((r >> 1) & 3);
      GLDS16(A + (size_t)(bm + r) * K + k0 + cl * 8, &As[(w * 32 + j * 16) * 32]);
      GLDS16(Wt + (size_t)(bn + r) * K + k0 + cl * 8, &Bs[(w * 32 + j * 16) * 32]);
    }
    __syncthreads();
    bf16x8 af[4], bfr[4];
#pragma unroll
    for (int i = 0; i < 4; ++i) {
      int ar = wm + i * 16 + (lane & 15);
      int ac = (lane >> 4) ^ ((ar >> 1) & 3);
      af[i] = *(const bf16x8*)&As[ar * 32 + ac * 8];
      int br = wn + i * 16 + (lane & 15);
      int bc = (lane >> 4) ^ ((br >> 1) & 3);
      bfr[i] = *(const bf16x8*)&Bs[br * 32 + bc * 8];
    }
#pragma unroll
    for (int mi = 0; mi < 4; ++mi)
#pragma unroll
      for (int ni = 0; ni < 4; ++ni)
        acc[mi][ni] = __builtin_amdgcn_mfma_f32_16x16x32_bf16(af[mi], bfr[ni], acc[mi][ni], 0, 0, 0);
    __syncthreads();
  }

#pragma unroll
  for (int mi = 0; mi < 4; ++mi) {
#pragma unroll
    for (int ni = 0; ni < 4; ++ni) {
#pragma unroll
      for (int r = 0; r < 4; ++r) {
        int row = bm + wm + mi * 16 + (lane >> 4) * 4 + r;
        int col = bn + wn + ni * 16 + (lane & 15);
        float v = acc[mi][ni][r];
        if (bias) v += bias[col];
        if (EPI == 1) v = 0.5f * v * (1.0f + erff(v * 0.70710678118f));
        size_t o = (size_t)row * N + col;
        if (EPI == 2) outF[o] = v + resid[o];
        else outB[o] = f2bf(v);
      }
    }
  }
}

// ---------------- repack qkv -> q,k [bh][n][dh] ----------------
__global__ __launch_bounds__(256) void repack_qk(const unsigned short* __restrict__ qkv,
                                                 unsigned short* __restrict__ q,
                                                 unsigned short* __restrict__ k) {
  int idx = blockIdx.x * 256 + threadIdx.x;  // over BB*SEQL*INNERD = 2^21
  int d = idx & (INNERD - 1);
  int n = (idx >> 9) & (SEQL - 1);
  int b = idx >> 20;
  int h = d >> 6, dh = d & 63;
  size_t src = (size_t)(b * SEQL + n) * 1536 + d;
  size_t dst = ((size_t)(b * NHEADS + h) * SEQL + n) * DHH + dh;
  q[dst] = qkv[src];
  k[dst] = qkv[src + INNERD];
}

// ---------------- v -> vt [bh][dh][n] via LDS transpose ----------------
__global__ __launch_bounds__(256) void transpose_v(const unsigned short* __restrict__ qkv,
                                                   unsigned short* __restrict__ vt) {
  __shared__ unsigned short t[64][65];
  int bh = blockIdx.x;  // 16
  int nt = blockIdx.y;  // 32
  int b = bh >> 3, h = bh & 7;
  for (int i = threadIdx.x; i < 64 * 64; i += 256) {
    int n = i >> 6, dh = i & 63;
    t[n][dh] = qkv[(size_t)(b * SEQL + nt * 64 + n) * 1536 + 2 * INNERD + h * 64 + dh];
  }
  __syncthreads();
  for (int i = threadIdx.x; i < 64 * 64; i += 256) {
    int dh = i >> 6, n = i & 63;
    vt[((size_t)bh * DHH + dh) * SEQL + nt * 64 + n] = t[n][dh];
  }
}

// ---------------- flash attention ----------------
__global__ __launch_bounds__(256)
void attn_k(const unsigned short* __restrict__ qg,
            const unsigned short* __restrict__ kg,
            const unsigned short* __restrict__ vtg,
            const int* __restrict__ mask,
            unsigned short* __restrict__ ctx) {
  __shared__ __align__(16) unsigned short Ks[64 * 64];
  __shared__ __align__(16) unsigned short Vts[64 * 64];
  __shared__ __align__(16) unsigned short Ps[4 * 16 * 64];
  const int tid = threadIdx.x, w = tid >> 6, lane = tid & 63;
  const int bh = blockIdx.y, b = bh >> 3;
  const int qt = blockIdx.x;
  const int q0 = qt * 64 + w * 16;

  bf16x8 qf[2];
#pragma unroll
  for (int kb = 0; kb < 2; ++kb) {
    int r = q0 + (lane & 15);
    qf[kb] = *(const bf16x8*)&qg[((size_t)bh * SEQL + r) * DHH + kb * 32 + (lane >> 4) * 8];
  }
  int mq[4];
#pragma unroll
  for (int r = 0; r < 4; ++r) mq[r] = mask[b * SEQL + q0 + (lane >> 4) * 4 + r];

  float m_s[4], l_s[4];
  f32x4 o[4] = {};
#pragma unroll
  for (int r = 0; r < 4; ++r) { m_s[r] = NEGF; l_s[r] = 0.f; }
  unsigned short* myP = &Ps[w * 16 * 64];

  for (int kt = 0; kt < SEQL / 64; ++kt) {
#pragma unroll
    for (int j = 0; j < 2; ++j) {
      int r = w * 16 + j * 8 + (lane >> 3);
      int cl = (lane & 7) ^ (r & 7);
      GLDS16(kg + ((size_t)bh * SEQL + kt * 64 + r) * DHH + cl * 8, &Ks[(w * 16 + j * 8) * 64]);
      GLDS16(vtg + ((size_t)bh * DHH + r) * SEQL + kt * 64 + cl * 8, &Vts[(w * 16 + j * 8) * 64]);
    }
    __syncthreads();

    f32x4 s[4] = {};
#pragma unroll
    for (int nt = 0; nt < 4; ++nt) {
#pragma unroll
      for (int kb = 0; kb < 2; ++kb) {
        int kr = nt * 16 + (lane & 15);
        int c = (kb * 4 + (lane >> 4)) ^ (kr & 7);
        bf16x8 kf = *(const bf16x8*)&Ks[kr * 64 + c * 8];
        s[nt] = __builtin_amdgcn_mfma_f32_16x16x32_bf16(qf[kb], kf, s[nt], 0, 0, 0);
      }
    }

    int mkk[4];
#pragma unroll
    for (int nt = 0; nt < 4; ++nt) mkk[nt] = mask[b * SEQL + kt * 64 + nt * 16 + (lane & 15)];

#pragma unroll
    for (int r = 0; r < 4; ++r) {
      float sv[4];
      float mx = NEGF;
#pragma unroll
      for (int nt = 0; nt < 4; ++nt) {
        float xv = s[nt][r] * SCALEF;
        xv = (mkk[nt] != 0 && mq[r] != 0) ? xv : NEGF;
        sv[nt] = xv;
        mx = fmaxf(mx, xv);
      }
      mx = fmaxf(mx, __shfl_xor(mx, 1));
      mx = fmaxf(mx, __shfl_xor(mx, 2));
      mx = fmaxf(mx, __shfl_xor(mx, 4));
      mx = fmaxf(mx, __shfl_xor(mx, 8));
      float mn = fmaxf(m_s[r], mx);
      float sf = __expf(m_s[r] - mn);
      m_s[r] = mn;
      float p[4], rs = 0.f;
#pragma unroll
      for (int nt = 0; nt < 4; ++nt) { p[nt] = __expf(sv[nt] - mn); rs += p[nt]; }
      rs += __shfl_xor(rs, 1);
      rs += __shfl_xor(rs, 2);
      rs += __shfl_xor(rs, 4);
      rs += __shfl_xor(rs, 8);
      l_s[r] = l_s[r] * sf + rs;
#pragma unroll
      for (int ni = 0; ni < 4; ++ni) o[ni][r] *= sf;
      int qr = (lane >> 4) * 4 + r;
#pragma unroll
      for (int nt = 0; nt < 4; ++nt) {
        int kv = nt * 16 + (lane & 15);
        int cc = (kv >> 3) ^ (qr & 7);
        myP[qr * 64 + cc * 8 + (kv & 7)] = f2bf(p[nt]);
      }
    }

#pragma unroll
    for (int kb = 0; kb < 2; ++kb) {
      int pr = lane & 15;
      int pc = (kb * 4 + (lane >> 4)) ^ (pr & 7);
      bf16x8 pf = *(const bf16x8*)&myP[pr * 64 + pc * 8];
#pragma unroll
      for (int ni = 0; ni < 4; ++ni) {
        int vr = ni * 16 + (lane & 15);
        int vc = (kb * 4 + (lane >> 4)) ^ (vr & 7);
        bf16x8 vf = *(const bf16x8*)&Vts[vr * 64 + vc * 8];
        o[ni] = __builtin_amdgcn_mfma_f32_16x16x32_bf16(pf, vf, o[ni], 0, 0, 0);
      }
    }
    __syncthreads();
  }

#pragma unroll
  for (int ni = 0; ni < 4; ++ni) {
#pragma unroll
    for (int r = 0; r < 4; ++r) {
      int row = qt * 64 + w * 16 + (lane >> 4) * 4 + r;
      int col = (bh & 7) * 64 + ni * 16 + (lane & 15);
      ctx[((size_t)b * SEQL + row) * INNERD + col] = f2bf(o[ni][r] / l_s[r]);
    }
  }
}

// ---------------- host ----------------
extern "C" void kernel_launch(void* const* d_in, const int* in_sizes, int n_in,
                              void* d_out, int out_size, void* d_ws, size_t ws_size,
                              hipStream_t stream) {
  (void)in_sizes; (void)n_in; (void)out_size; (void)ws_size;
  const float* x_in = (const float*)d_in[0];
  const int* mask = (const int*)d_in[1];
  const float* qkv_w = (const float*)d_in[2];
  const float* out_w = (const float*)d_in[3];
  const float* out_b = (const float*)d_in[4];
  const float* ff_w1 = (const float*)d_in[5];
  const float* ff_b1 = (const float*)d_in[6];
  const float* ff_w2 = (const float*)d_in[7];
  const float* ff_b2 = (const float*)d_in[8];
  const float* ad1w = (const float*)d_in[9];
  const float* ad1b = (const float*)d_in[10];
  const float* ad2w = (const float*)d_in[11];
  const float* ad2b = (const float*)d_in[12];

  char* ws = (char*)d_ws;
  size_t off = 0;
  auto alloc = [&](size_t bytes) {
    char* p = ws + off;
    off = (off + bytes + 255) & ~(size_t)255;
    return p;
  };
  unsigned short* wtQ = (unsigned short*)alloc((size_t)DEPTHL * 1536 * 512 * 2);
  unsigned short* wtO = (unsigned short*)alloc((size_t)DEPTHL * 512 * 512 * 2);
  unsigned short* wtF1 = (unsigned short*)alloc((size_t)DEPTHL * 2048 * 512 * 2);
  unsigned short* wtF2 = (unsigned short*)alloc((size_t)DEPTHL * 512 * 2048 * 2);
  float* xc = (float*)alloc((size_t)ROWS * DIMM * 4);
  unsigned short* hbf = (unsigned short*)alloc((size_t)ROWS * DIMM * 2);
  unsigned short* qkvbf = (unsigned short*)alloc((size_t)ROWS * 1536 * 2);
  char* region2 = alloc((size_t)4 * 16 * SEQL * DHH * 2);  // q,k,vt,ctx OR h1
  unsigned short* qb = (unsigned short*)region2;
  unsigned short* kb = qb + (size_t)16 * SEQL * DHH;
  unsigned short* vtb = kb + (size_t)16 * SEQL * DHH;
  unsigned short* ctxb = vtb + (size_t)16 * SEQL * DHH;
  unsigned short* h1bf = (unsigned short*)region2;  // aliases q/k/vt/ctx (disjoint lifetime)
  float* p1 = (float*)alloc((size_t)BB * 32 * DIMM * 4);
  float* p2 = (float*)alloc((size_t)BB * 32 * DIMM * 4);
  float* alpha = (float*)alloc((size_t)BB * DIMM * 4);
  float* beta = (float*)alloc((size_t)BB * DIMM * 4);

  // x working copy
  hipMemcpyAsync(xc, x_in, (size_t)ROWS * DIMM * 4, hipMemcpyDeviceToDevice, stream);

  // weights -> bf16 transposed [N][K]
  wtrans<<<dim3(512 / 32, 1536 / 32, DEPTHL), 256, 0, stream>>>(qkv_w, wtQ, 512, 1536);
  wtrans<<<dim3(512 / 32, 512 / 32, DEPTHL), 256, 0, stream>>>(out_w, wtO, 512, 512);
  wtrans<<<dim3(512 / 32, 2048 / 32, DEPTHL), 256, 0, stream>>>(ff_w1, wtF1, 512, 2048);
  wtrans<<<dim3(2048 / 32, 512 / 32, DEPTHL), 256, 0, stream>>>(ff_w2, wtF2, 2048, 512);

  for (int l = 0; l < DEPTHL; ++l) {
    // adain 1
    adain_p1<<<dim3(32, BB), 512, 0, stream>>>(xc, p1, p2);
    adain_p2<<<BB, 512, 0, stream>>>(p1, p2, ad1w + l * BB * DIMM, ad1b + l * BB * DIMM, alpha, beta);
    adain_apply<<<8192, 256, 0, stream>>>(xc, alpha, beta, hbf);
    // qkv
    gemm_k<0><<<dim3(1536 / 128, ROWS / 128), 256, 0, stream>>>(
        hbf, wtQ + (size_t)l * 1536 * 512, nullptr, nullptr, nullptr, qkvbf, 1536, 512);
    repack_qk<<<8192, 256, 0, stream>>>(qkvbf, qb, kb);
    transpose_v<<<dim3(16, 32), 256, 0, stream>>>(qkvbf, vtb);
    attn_k<<<dim3(SEQL / 64, 16), 256, 0, stream>>>(qb, kb, vtb, mask, ctxb);
    // out proj + residual (in place on xc)
    gemm_k<2><<<dim3(512 / 128, ROWS / 128), 256, 0, stream>>>(
        ctxb, wtO + (size_t)l * 512 * 512, out_b + l * DIMM, xc, xc, nullptr, 512, 512);
    // adain 2
    adain_p1<<<dim3(32, BB), 512, 0, stream>>>(xc, p1, p2);
    adain_p2<<<BB, 512, 0, stream>>>(p1, p2, ad2w + l * BB * DIMM, ad2b + l * BB * DIMM, alpha, beta);
    adain_apply<<<8192, 256, 0, stream>>>(xc, alpha, beta, hbf);
    // ff1 (gelu) -> h1
    gemm_k<1><<<dim3(2048 / 128, ROWS / 128), 256, 0, stream>>>(
        hbf, wtF1 + (size_t)l * 2048 * 512, ff_b1 + l * MLPD, nullptr, nullptr, h1bf, 2048, 512);
    // ff2 + residual
    float* xout = (l == DEPTHL - 1) ? (float*)d_out : xc;
    gemm_k<2><<<dim3(512 / 128, ROWS / 128), 256, 0, stream>>>(
        h1bf, wtF2 + (size_t)l * 512 * 2048, ff_b2 + l * DIMM, xc, xout, nullptr, 512, 2048);
  }
}

// Round 2
// 499.685 us; speedup vs baseline: 1.0844x; 1.0844x over previous
//
#include <hip/hip_runtime.h>
#include <hip/hip_bf16.h>

#define DEPTHL 2
#define DIMM   512
#define NHEADS 8
#define DHH    64
#define INNERD 512
#define MLPD   2048
#define BB     2
#define SEQL   2048
#define ROWS   (BB*SEQL)
#define NEGF   (-3.402823466e38f)
#define SCALEF 0.125f
#define NSPLIT 4
#define KPS    (SEQL / NSPLIT)

typedef __attribute__((ext_vector_type(4))) float f32x4;
typedef __attribute__((ext_vector_type(8))) __bf16 bf16x8;

#define GLDS16(g, l) __builtin_amdgcn_global_load_lds((const __attribute__((address_space(1))) void*)(g), (__attribute__((address_space(3))) void*)(l), 16, 0, 0)

__device__ __forceinline__ unsigned short f2bf(float f) {
  union { float f; unsigned int u; } v; v.f = f;
  unsigned int r = v.u + 0x7fffu + ((v.u >> 16) & 1u);
  return (unsigned short)(r >> 16);
}
__device__ __forceinline__ float bf2f(unsigned short h) {
  union { unsigned int u; float f; } v; v.u = ((unsigned int)h) << 16; return v.f;
}
__device__ __forceinline__ unsigned int pkbf(float a, float b) {
  return (unsigned int)f2bf(a) | ((unsigned int)f2bf(b) << 16);
}

// ---------------- weight transpose fp32[K][N] -> bf16[N][K] ----------------
__global__ __launch_bounds__(256) void wtrans(const float* __restrict__ wsrc,
                                              unsigned short* __restrict__ wdst,
                                              int K, int N) {
  __shared__ float t[32][33];
  const float* src = wsrc + (size_t)blockIdx.z * K * N;
  unsigned short* dst = wdst + (size_t)blockIdx.z * K * N;
  int k0 = blockIdx.x * 32, n0 = blockIdx.y * 32;
  int tx = threadIdx.x & 31, ty = threadIdx.x >> 5;  // 32x8
#pragma unroll
  for (int j = 0; j < 32; j += 8)
    t[ty + j][tx] = src[(size_t)(k0 + ty + j) * N + n0 + tx];
  __syncthreads();
#pragma unroll
  for (int j = 0; j < 32; j += 8)
    dst[(size_t)(n0 + ty + j) * K + k0 + tx] = f2bf(t[tx][ty + j]);
}

// ---------------- adain ----------------
__global__ __launch_bounds__(512) void adain_p1(const float* __restrict__ x,
                                                float* __restrict__ p1, float* __restrict__ p2) {
  int d = threadIdx.x, c = blockIdx.x, b = blockIdx.y;
  const float* xp = x + ((size_t)b * SEQL + c * 64) * DIMM + d;
  float s = 0.f, s2 = 0.f;
  for (int i = 0; i < 64; ++i) { float v = xp[(size_t)i * DIMM]; s += v; s2 += v * v; }
  p1[(b * 32 + c) * DIMM + d] = s;
  p2[(b * 32 + c) * DIMM + d] = s2;
}

__global__ __launch_bounds__(512) void adain_p2(const float* __restrict__ p1, const float* __restrict__ p2,
                                                const float* __restrict__ w, const float* __restrict__ bi,
                                                float* __restrict__ alpha, float* __restrict__ beta) {
  int d = threadIdx.x, b = blockIdx.x;
  float s = 0.f, s2 = 0.f;
  for (int c = 0; c < 32; ++c) { s += p1[(b * 32 + c) * DIMM + d]; s2 += p2[(b * 32 + c) * DIMM + d]; }
  float mean = s * (1.0f / SEQL);
  float var = s2 * (1.0f / SEQL) - mean * mean;
  float a = w[b * DIMM + d] * rsqrtf(var + 1e-6f);
  alpha[b * DIMM + d] = a;
  beta[b * DIMM + d] = bi[b * DIMM + d] - mean * a;
}

__global__ __launch_bounds__(256) void adain_apply(const float* __restrict__ x,
                                                   const float* __restrict__ alpha, const float* __restrict__ beta,
                                                   unsigned short* __restrict__ hb) {
  int idx = blockIdx.x * 256 + threadIdx.x;  // over ROWS*DIMM = 2^21
  int d = idx & (DIMM - 1);
  int b = idx >> 20;  // SEQL*DIMM = 2^20
  hb[idx] = f2bf(x[idx] * alpha[b * DIMM + d] + beta[b * DIMM + d]);
}

// ---------------- mask -> additive float ----------------
__global__ __launch_bounds__(256) void maskbuild(const int* __restrict__ mask, float* __restrict__ maskadd) {
  int i = blockIdx.x * 256 + threadIdx.x;  // B*N = 4096
  maskadd[i] = mask[i] ? 0.f : NEGF;
}

// ---------------- GEMM: out = A[M,K](bf16) @ Wt[N,K]^T(bf16) (+bias)(+gelu)(+resid) ----------------
template <int EPI>
__global__ __launch_bounds__(256)
void gemm_k(const unsigned short* __restrict__ A,
            const unsigned short* __restrict__ Wt,
            const float* __restrict__ bias,
            const float* __restrict__ resid,
            float* __restrict__ outF,
            unsigned short* __restrict__ outB,
            int N, int K) {
  __shared__ __align__(16) unsigned short As[128 * 32];
  __shared__ __align__(16) unsigned short Bs[128 * 32];
  const int tid = threadIdx.x;
  const int w = tid >> 6, lane = tid & 63;
  const int bm = blockIdx.y * 128, bn = blockIdx.x * 128;
  const int wm = (w >> 1) * 64, wn = (w & 1) * 64;

  f32x4 acc[4][4] = {};

  const int sr0 = w * 32 + (lane >> 2);
  const int sc = lane & 3;

  for (int k0 = 0; k0 < K; k0 += 32) {
#pragma unroll
    for (int j = 0; j < 2; ++j) {
      int r = sr0 + j * 16;
      int cl = sc ^ ((r >> 1) & 3);
      GLDS16(A + (size_t)(bm + r) * K + k0 + cl * 8, &As[(w * 32 + j * 16) * 32]);
      GLDS16(Wt + (size_t)(bn + r) * K + k0 + cl * 8, &Bs[(w * 32 + j * 16) * 32]);
    }
    __syncthreads();
    bf16x8 af[4], bfr[4];
#pragma unroll
    for (int i = 0; i < 4; ++i) {
      int ar = wm + i * 16 + (lane & 15);
      int ac = (lane >> 4) ^ ((ar >> 1) & 3);
      af[i] = *(const bf16x8*)&As[ar * 32 + ac * 8];
      int br = wn + i * 16 + (lane & 15);
      int bc = (lane >> 4) ^ ((br >> 1) & 3);
      bfr[i] = *(const bf16x8*)&Bs[br * 32 + bc * 8];
    }
#pragma unroll
    for (int mi = 0; mi < 4; ++mi)
#pragma unroll
      for (int ni = 0; ni < 4; ++ni)
        acc[mi][ni] = __builtin_amdgcn_mfma_f32_16x16x32_bf16(af[mi], bfr[ni], acc[mi][ni], 0, 0, 0);
    __syncthreads();
  }

#pragma unroll
  for (int mi = 0; mi < 4; ++mi) {
#pragma unroll
    for (int ni = 0; ni < 4; ++ni) {
#pragma unroll
      for (int r = 0; r < 4; ++r) {
        int row = bm + wm + mi * 16 + (lane >> 4) * 4 + r;
        int col = bn + wn + ni * 16 + (lane & 15);
        float v = acc[mi][ni][r];
        if (bias) v += bias[col];
        if (EPI == 1) v = 0.5f * v * (1.0f + erff(v * 0.70710678118f));
        size_t o = (size_t)row * N + col;
        if (EPI == 2) outF[o] = v + resid[o];
        else outB[o] = f2bf(v);
      }
    }
  }
}

// ---------------- repack qkv -> q,k [bh][n][dh] ----------------
__global__ __launch_bounds__(256) void repack_qk(const unsigned short* __restrict__ qkv,
                                                 unsigned short* __restrict__ q,
                                                 unsigned short* __restrict__ k) {
  int idx = blockIdx.x * 256 + threadIdx.x;  // over BB*SEQL*INNERD = 2^21
  int d = idx & (INNERD - 1);
  int n = (idx >> 9) & (SEQL - 1);
  int b = idx >> 20;
  int h = d >> 6, dh = d & 63;
  size_t src = (size_t)(b * SEQL + n) * 1536 + d;
  size_t dst = ((size_t)(b * NHEADS + h) * SEQL + n) * DHH + dh;
  q[dst] = qkv[src];
  k[dst] = qkv[src + INNERD];
}

// ---------------- v -> vt [bh][dh][n] via LDS transpose ----------------
__global__ __launch_bounds__(256) void transpose_v(const unsigned short* __restrict__ qkv,
                                                   unsigned short* __restrict__ vt) {
  __shared__ unsigned short t[64][65];
  int bh = blockIdx.x;  // 16
  int nt = blockIdx.y;  // 32
  int b = bh >> 3, h = bh & 7;
  for (int i = threadIdx.x; i < 64 * 64; i += 256) {
    int n = i >> 6, dh = i & 63;
    t[n][dh] = qkv[(size_t)(b * SEQL + nt * 64 + n) * 1536 + 2 * INNERD + h * 64 + dh];
  }
  __syncthreads();
  for (int i = threadIdx.x; i < 64 * 64; i += 256) {
    int dh = i >> 6, n = i & 63;
    vt[((size_t)bh * DHH + dh) * SEQL + nt * 64 + n] = t[n][dh];
  }
}

// ---------------- flash attention, KV-split, swapped-QK^T softmax ----------------
__global__ __launch_bounds__(256, 4)
void attn_split(const unsigned short* __restrict__ qg,
                const unsigned short* __restrict__ kg,
                const unsigned short* __restrict__ vtg,
                const float* __restrict__ maskadd,
                unsigned short* __restrict__ opart,  // [NSPLIT][16][SEQL][DHH] bf16 (unnormalized)
                float* __restrict__ mlpart) {       // [NSPLIT][16][SEQL][2]
  __shared__ __align__(16) unsigned short Ks[64 * 64];
  __shared__ __align__(16) unsigned short Vts[64 * 64];
  __shared__ __align__(16) unsigned short Ps[4 * 16 * 64];
  const int tid = threadIdx.x, w = tid >> 6, lane = tid & 63;
  const int g = lane >> 4, c = lane & 15;
  const int bh = blockIdx.y, b = bh >> 3;
  const int qt = blockIdx.x;
  const int split = blockIdx.z;
  const int kv0 = split * KPS;
  const int q0 = qt * 64 + w * 16;
  const float* maskb = maskadd + b * SEQL;

  bf16x8 qf[2];
#pragma unroll
  for (int kb = 0; kb < 2; ++kb)
    qf[kb] = *(const bf16x8*)&qg[((size_t)bh * SEQL + q0 + c) * DHH + kb * 32 + g * 8];
  const float mq = maskb[q0 + c];

  float m_q = NEGF, l_q = 0.f;
  f32x4 o[4] = {};
  unsigned short* myP = &Ps[w * 1024];

  for (int kt = 0; kt < KPS / 64; ++kt) {
    // stage K tile [64 k][64 dh] and Vt tile [64 d][64 n], slot-swizzled source
#pragma unroll
    for (int j = 0; j < 2; ++j) {
      int r = w * 16 + j * 8 + (lane >> 3);
      int cl = (lane & 7) ^ (r & 7);
      GLDS16(kg + ((size_t)bh * SEQL + kv0 + kt * 64 + r) * DHH + cl * 8, &Ks[(w * 16 + j * 8) * 64]);
      GLDS16(vtg + ((size_t)bh * DHH + r) * SEQL + kv0 + kt * 64 + cl * 8, &Vts[(w * 16 + j * 8) * 64]);
    }
    __syncthreads();

    // S^T = K @ Q^T : lane holds S[k = nt*16+g*4+r][q = c]
    f32x4 sT[4] = {};
#pragma unroll
    for (int nt = 0; nt < 4; ++nt) {
#pragma unroll
      for (int kb = 0; kb < 2; ++kb) {
        int kr = nt * 16 + c;
        int cs = (kb * 4 + g) ^ (kr & 7);
        bf16x8 kf = *(const bf16x8*)&Ks[kr * 64 + cs * 8];
        sT[nt] = __builtin_amdgcn_mfma_f32_16x16x32_bf16(kf, qf[kb], sT[nt], 0, 0, 0);
      }
    }

    // masked scale + in-lane row max
    float mx = NEGF;
#pragma unroll
    for (int nt = 0; nt < 4; ++nt) {
      f32x4 mk = *(const f32x4*)&maskb[kv0 + kt * 64 + nt * 16 + g * 4];
#pragma unroll
      for (int r = 0; r < 4; ++r) {
        float x = sT[nt][r] * SCALEF + fmaxf(mq + mk[r], NEGF);
        sT[nt][r] = x;
        mx = fmaxf(mx, x);
      }
    }
    mx = fmaxf(mx, __shfl_xor(mx, 16));
    mx = fmaxf(mx, __shfl_xor(mx, 32));
    float mn = fmaxf(m_q, mx);
    float sf = __expf(m_q - mn);
    m_q = mn;

    // P = exp(S - m), pack to bf16, write to wave-private LDS P[q][k] (slot-swizzled)
    float rs = 0.f;
#pragma unroll
    for (int nt = 0; nt < 4; ++nt) {
      float pv0 = __expf(sT[nt][0] - mn), pv1 = __expf(sT[nt][1] - mn);
      float pv2 = __expf(sT[nt][2] - mn), pv3 = __expf(sT[nt][3] - mn);
      rs += (pv0 + pv1) + (pv2 + pv3);
      unsigned int lo = pkbf(pv0, pv1), hi = pkbf(pv2, pv3);
      int off = c * 64 + (((nt * 2 + (g >> 1)) ^ (c & 7)) << 3) + ((g & 1) << 2);
      *(uint2*)(myP + off) = make_uint2(lo, hi);
    }
    rs += __shfl_xor(rs, 16);
    rs += __shfl_xor(rs, 32);
    l_q = l_q * sf + rs;

    // rescale O (O rows are q = g*4+r; sf is indexed by q = lane&15, replicated over groups)
    float sfq[4];
#pragma unroll
    for (int r = 0; r < 4; ++r) sfq[r] = __shfl(sf, g * 4 + r);
#pragma unroll
    for (int ni = 0; ni < 4; ++ni)
#pragma unroll
      for (int r = 0; r < 4; ++r) o[ni][r] *= sfq[r];

    // PV: A = P (from wave-private LDS), B = Vt
#pragma unroll
    for (int kb = 0; kb < 2; ++kb) {
      bf16x8 pf = *(const bf16x8*)&myP[c * 64 + (((kb * 4 + g) ^ (c & 7)) << 3)];
#pragma unroll
      for (int ni = 0; ni < 4; ++ni) {
        int vr = ni * 16 + c;
        int vc = (kb * 4 + g) ^ (vr & 7);
        bf16x8 vf = *(const bf16x8*)&Vts[vr * 64 + vc * 8];
        o[ni] = __builtin_amdgcn_mfma_f32_16x16x32_bf16(pf, vf, o[ni], 0, 0, 0);
      }
    }
    __syncthreads();
  }

  // write unnormalized partials
  const size_t pb = ((size_t)split * 16 + bh) * SEQL;
#pragma unroll
  for (int ni = 0; ni < 4; ++ni)
#pragma unroll
    for (int r = 0; r < 4; ++r)
      opart[(pb + q0 + g * 4 + r) * DHH + ni * 16 + c] = f2bf(o[ni][r]);
  if (lane < 16) {
    size_t mo = (pb + q0 + lane) * 2;
    mlpart[mo] = m_q;
    mlpart[mo + 1] = l_q;
  }
}

__global__ __launch_bounds__(256) void attn_combine(const unsigned short* __restrict__ opart,
                                                    const float* __restrict__ mlpart,
                                                    unsigned short* __restrict__ ctx) {
  int idx = blockIdx.x * 256 + threadIdx.x;  // 16*SEQL*DHH = 2M
  int d = idx & 63, q = (idx >> 6) & (SEQL - 1), bh = idx >> 17;
  float m[NSPLIT], l[NSPLIT], M = NEGF;
#pragma unroll
  for (int s = 0; s < NSPLIT; ++s) {
    size_t mo = (((size_t)s * 16 + bh) * SEQL + q) * 2;
    m[s] = mlpart[mo];
    l[s] = mlpart[mo + 1];
    M = fmaxf(M, m[s]);
  }
  float L = 0.f, ov = 0.f;
#pragma unroll
  for (int s = 0; s < NSPLIT; ++s) {
    float e = __expf(m[s] - M);
    L += l[s] * e;
    ov += bf2f(opart[(((size_t)s * 16 + bh) * SEQL + q) * DHH + d]) * e;
  }
  int b = bh >> 3, h = bh & 7;
  ctx[((size_t)(b * SEQL + q)) * INNERD + h * 64 + d] = f2bf(ov / L);
}

// ---------------- host ----------------
extern "C" void kernel_launch(void* const* d_in, const int* in_sizes, int n_in,
                              void* d_out, int out_size, void* d_ws, size_t ws_size,
                              hipStream_t stream) {
  (void)in_sizes; (void)n_in; (void)out_size; (void)ws_size;
  const float* x_in = (const float*)d_in[0];
  const int* mask = (const int*)d_in[1];
  const float* qkv_w = (const float*)d_in[2];
  const float* out_w = (const float*)d_in[3];
  const float* out_b = (const float*)d_in[4];
  const float* ff_w1 = (const float*)d_in[5];
  const float* ff_b1 = (const float*)d_in[6];
  const float* ff_w2 = (const float*)d_in[7];
  const float* ff_b2 = (const float*)d_in[8];
  const float* ad1w = (const float*)d_in[9];
  const float* ad1b = (const float*)d_in[10];
  const float* ad2w = (const float*)d_in[11];
  const float* ad2b = (const float*)d_in[12];

  char* ws = (char*)d_ws;
  size_t off = 0;
  auto alloc = [&](size_t bytes) {
    char* p = ws + off;
    off = (off + bytes + 255) & ~(size_t)255;
    return p;
  };
  unsigned short* wtQ = (unsigned short*)alloc((size_t)DEPTHL * 1536 * 512 * 2);
  unsigned short* wtO = (unsigned short*)alloc((size_t)DEPTHL * 512 * 512 * 2);
  unsigned short* wtF1 = (unsigned short*)alloc((size_t)DEPTHL * 2048 * 512 * 2);
  unsigned short* wtF2 = (unsigned short*)alloc((size_t)DEPTHL * 512 * 2048 * 2);
  float* xc = (float*)alloc((size_t)ROWS * DIMM * 4);
  unsigned short* hbf = (unsigned short*)alloc((size_t)ROWS * DIMM * 2);
  unsigned short* qkvbf = (unsigned short*)alloc((size_t)ROWS * 1536 * 2);
  char* region2 = alloc((size_t)4 * 16 * SEQL * DHH * 2);  // q,k,vt,ctx OR h1
  unsigned short* qb = (unsigned short*)region2;
  unsigned short* kb = qb + (size_t)16 * SEQL * DHH;
  unsigned short* vtb = kb + (size_t)16 * SEQL * DHH;
  unsigned short* ctxb = vtb + (size_t)16 * SEQL * DHH;
  unsigned short* h1bf = (unsigned short*)region2;  // aliases q/k/vt/ctx (disjoint lifetime)
  float* p1 = (float*)alloc((size_t)BB * 32 * DIMM * 4);
  float* p2 = (float*)alloc((size_t)BB * 32 * DIMM * 4);
  float* alpha = (float*)alloc((size_t)BB * DIMM * 4);
  float* beta = (float*)alloc((size_t)BB * DIMM * 4);
  float* maskadd = (float*)alloc((size_t)BB * SEQL * 4);
  unsigned short* opart = (unsigned short*)alloc((size_t)NSPLIT * 16 * SEQL * DHH * 2);
  float* mlpart = (float*)alloc((size_t)NSPLIT * 16 * SEQL * 2 * 4);

  // x working copy
  hipMemcpyAsync(xc, x_in, (size_t)ROWS * DIMM * 4, hipMemcpyDeviceToDevice, stream);

  // weights -> bf16 transposed [N][K]
  wtrans<<<dim3(512 / 32, 1536 / 32, DEPTHL), 256, 0, stream>>>(qkv_w, wtQ, 512, 1536);
  wtrans<<<dim3(512 / 32, 512 / 32, DEPTHL), 256, 0, stream>>>(out_w, wtO, 512, 512);
  wtrans<<<dim3(512 / 32, 2048 / 32, DEPTHL), 256, 0, stream>>>(ff_w1, wtF1, 512, 2048);
  wtrans<<<dim3(2048 / 32, 512 / 32, DEPTHL), 256, 0, stream>>>(ff_w2, wtF2, 2048, 512);
  maskbuild<<<BB * SEQL / 256, 256, 0, stream>>>(mask, maskadd);

  for (int l = 0; l < DEPTHL; ++l) {
    // adain 1
    adain_p1<<<dim3(32, BB), 512, 0, stream>>>(xc, p1, p2);
    adain_p2<<<BB, 512, 0, stream>>>(p1, p2, ad1w + l * BB * DIMM, ad1b + l * BB * DIMM, alpha, beta);
    adain_apply<<<8192, 256, 0, stream>>>(xc, alpha, beta, hbf);
    // qkv
    gemm_k<0><<<dim3(1536 / 128, ROWS / 128), 256, 0, stream>>>(
        hbf, wtQ + (size_t)l * 1536 * 512, nullptr, nullptr, nullptr, qkvbf, 1536, 512);
    repack_qk<<<8192, 256, 0, stream>>>(qkvbf, qb, kb);
    transpose_v<<<dim3(16, 32), 256, 0, stream>>>(qkvbf, vtb);
    attn_split<<<dim3(SEQL / 64, 16, NSPLIT), 256, 0, stream>>>(qb, kb, vtb, maskadd, opart, mlpart);
    attn_combine<<<16 * SEQL * DHH / 256, 256, 0, stream>>>(opart, mlpart, ctxb);
    // out proj + residual (in place on xc)
    gemm_k<2><<<dim3(512 / 128, ROWS / 128), 256, 0, stream>>>(
        ctxb, wtO + (size_t)l * 512 * 512, out_b + l * DIMM, xc, xc, nullptr, 512, 512);
    // adain 2
    adain_p1<<<dim3(32, BB), 512, 0, stream>>>(xc, p1, p2);
    adain_p2<<<BB, 512, 0, stream>>>(p1, p2, ad2w + l * BB * DIMM, ad2b + l * BB * DIMM, alpha, beta);
    adain_apply<<<8192, 256, 0, stream>>>(xc, alpha, beta, hbf);
    // ff1 (gelu) -> h1
    gemm_k<1><<<dim3(2048 / 128, ROWS / 128), 256, 0, stream>>>(
        hbf, wtF1 + (size_t)l * 2048 * 512, ff_b1 + l * MLPD, nullptr, nullptr, h1bf, 2048, 512);
    // ff2 + residual
    float* xout = (l == DEPTHL - 1) ? (float*)d_out : xc;
    gemm_k<2><<<dim3(512 / 128, ROWS / 128), 256, 0, stream>>>(
        h1bf, wtF2 + (size_t)l * 512 * 2048, ff_b2 + l * DIMM, xc, xout, nullptr, 512, 2048);
  }
}

// Round 3
// 475.495 us; speedup vs baseline: 1.1396x; 1.0509x over previous
//
#include <hip/hip_runtime.h>
#include <hip/hip_bf16.h>

#define DEPTHL 2
#define DIMM   512
#define NHEADS 8
#define DHH    64
#define INNERD 512
#define MLPD   2048
#define BB     2
#define SEQL   2048
#define ROWS   (BB*SEQL)
#define NEGF   (-3.402823466e38f)
#define SCALEF 0.125f
#define NSPLIT 4
#define KPS    (SEQL / NSPLIT)

typedef __attribute__((ext_vector_type(4))) float f32x4;
typedef __attribute__((ext_vector_type(8))) __bf16 bf16x8;

#define GLDS16(g, l) __builtin_amdgcn_global_load_lds((const __attribute__((address_space(1))) void*)(g), (__attribute__((address_space(3))) void*)(l), 16, 0, 0)

__device__ __forceinline__ unsigned short f2bf(float f) {
  union { float f; unsigned int u; } v; v.f = f;
  unsigned int r = v.u + 0x7fffu + ((v.u >> 16) & 1u);
  return (unsigned short)(r >> 16);
}
__device__ __forceinline__ float bf2f(unsigned short h) {
  union { unsigned int u; float f; } v; v.u = ((unsigned int)h) << 16; return v.f;
}
__device__ __forceinline__ unsigned int pkbf(float a, float b) {
  return (unsigned int)f2bf(a) | ((unsigned int)f2bf(b) << 16);
}

// ---------------- weight transpose fp32[K][N] -> bf16[N][K] ----------------
__global__ __launch_bounds__(256) void wtrans(const float* __restrict__ wsrc,
                                              unsigned short* __restrict__ wdst,
                                              int K, int N) {
  __shared__ float t[32][33];
  const float* src = wsrc + (size_t)blockIdx.z * K * N;
  unsigned short* dst = wdst + (size_t)blockIdx.z * K * N;
  int k0 = blockIdx.x * 32, n0 = blockIdx.y * 32;
  int tx = threadIdx.x & 31, ty = threadIdx.x >> 5;  // 32x8
#pragma unroll
  for (int j = 0; j < 32; j += 8)
    t[ty + j][tx] = src[(size_t)(k0 + ty + j) * N + n0 + tx];
  __syncthreads();
#pragma unroll
  for (int j = 0; j < 32; j += 8)
    dst[(size_t)(n0 + ty + j) * K + k0 + tx] = f2bf(t[tx][ty + j]);
}

// ---------------- adain ----------------
__global__ __launch_bounds__(512) void adain_p1(const float* __restrict__ x,
                                                float* __restrict__ p1, float* __restrict__ p2) {
  int d = threadIdx.x, c = blockIdx.x, b = blockIdx.y;
  const float* xp = x + ((size_t)b * SEQL + c * 64) * DIMM + d;
  float s = 0.f, s2 = 0.f;
  for (int i = 0; i < 64; ++i) { float v = xp[(size_t)i * DIMM]; s += v; s2 += v * v; }
  p1[(b * 32 + c) * DIMM + d] = s;
  p2[(b * 32 + c) * DIMM + d] = s2;
}

__global__ __launch_bounds__(512) void adain_p2(const float* __restrict__ p1, const float* __restrict__ p2,
                                                const float* __restrict__ w, const float* __restrict__ bi,
                                                float* __restrict__ alpha, float* __restrict__ beta) {
  int d = threadIdx.x, b = blockIdx.x;
  float s = 0.f, s2 = 0.f;
  for (int c = 0; c < 32; ++c) { s += p1[(b * 32 + c) * DIMM + d]; s2 += p2[(b * 32 + c) * DIMM + d]; }
  float mean = s * (1.0f / SEQL);
  float var = s2 * (1.0f / SEQL) - mean * mean;
  float a = w[b * DIMM + d] * rsqrtf(var + 1e-6f);
  alpha[b * DIMM + d] = a;
  beta[b * DIMM + d] = bi[b * DIMM + d] - mean * a;
}

__global__ __launch_bounds__(256) void adain_apply(const float* __restrict__ x,
                                                   const float* __restrict__ alpha, const float* __restrict__ beta,
                                                   unsigned short* __restrict__ hb) {
  int idx = blockIdx.x * 256 + threadIdx.x;  // over ROWS*DIMM = 2^21
  int d = idx & (DIMM - 1);
  int b = idx >> 20;  // SEQL*DIMM = 2^20
  hb[idx] = f2bf(x[idx] * alpha[b * DIMM + d] + beta[b * DIMM + d]);
}

// ---------------- mask -> additive float ----------------
__global__ __launch_bounds__(256) void maskbuild(const int* __restrict__ mask, float* __restrict__ maskadd) {
  int i = blockIdx.x * 256 + threadIdx.x;  // B*N = 4096
  maskadd[i] = mask[i] ? 0.f : NEGF;
}

// ---------------- GEMM: out = A[M,K](bf16) @ Wt[N,K]^T(bf16) (+bias)(+gelu)(+resid) ----------------
// 2-phase double-buffered pipeline + XCD-chunked tile remap (grid.y must be %8)
template <int EPI>
__global__ __launch_bounds__(256)
void gemm_k(const unsigned short* __restrict__ A,
            const unsigned short* __restrict__ Wt,
            const float* __restrict__ bias,
            const float* __restrict__ resid,
            float* __restrict__ outF,
            unsigned short* __restrict__ outB,
            int N, int K) {
  __shared__ __align__(16) unsigned short As[2][128 * 32];
  __shared__ __align__(16) unsigned short Bs[2][128 * 32];
  const int tid = threadIdx.x;
  const int w = tid >> 6, lane = tid & 63;

  // XCD-aware remap: flat id f -> xcd grp = f&7 owns 4 contiguous row-panels.
  unsigned int f = blockIdx.y * gridDim.x + blockIdx.x;
  unsigned int grp = f & 7u, idx = f >> 3;
  unsigned int rpx = gridDim.y >> 3;  // = 4
  unsigned int by = grp * rpx + idx / gridDim.x;
  unsigned int bx = idx % gridDim.x;

  const int bm = by * 128, bn = bx * 128;
  const int wm = (w >> 1) * 64, wn = (w & 1) * 64;

  f32x4 acc[4][4] = {};

  const int sr0 = w * 32 + (lane >> 2);
  const int sc = lane & 3;

  auto stage = [&](int buf, int k0) {
#pragma unroll
    for (int j = 0; j < 2; ++j) {
      int r = sr0 + j * 16;
      int cl = sc ^ ((r >> 1) & 3);
      GLDS16(A + (size_t)(bm + r) * K + k0 + cl * 8, &As[buf][(w * 32 + j * 16) * 32]);
      GLDS16(Wt + (size_t)(bn + r) * K + k0 + cl * 8, &Bs[buf][(w * 32 + j * 16) * 32]);
    }
  };

  stage(0, 0);
  __syncthreads();  // implicit vmcnt(0) drain -> buf0 ready
  int cur = 0;

  for (int k0 = 0; k0 < K; k0 += 32) {
    if (k0 + 32 < K) stage(cur ^ 1, k0 + 32);  // prefetch next tile, in flight during compute
    bf16x8 af[4], bfr[4];
#pragma unroll
    for (int i = 0; i < 4; ++i) {
      int ar = wm + i * 16 + (lane & 15);
      int ac = (lane >> 4) ^ ((ar >> 1) & 3);
      af[i] = *(const bf16x8*)&As[cur][ar * 32 + ac * 8];
      int br = wn + i * 16 + (lane & 15);
      int bc = (lane >> 4) ^ ((br >> 1) & 3);
      bfr[i] = *(const bf16x8*)&Bs[cur][br * 32 + bc * 8];
    }
#pragma unroll
    for (int mi = 0; mi < 4; ++mi)
#pragma unroll
      for (int ni = 0; ni < 4; ++ni)
        acc[mi][ni] = __builtin_amdgcn_mfma_f32_16x16x32_bf16(af[mi], bfr[ni], acc[mi][ni], 0, 0, 0);
    __syncthreads();  // all waves done reading buf[cur] AND prefetch loads drained
    cur ^= 1;
  }

#pragma unroll
  for (int mi = 0; mi < 4; ++mi) {
#pragma unroll
    for (int ni = 0; ni < 4; ++ni) {
#pragma unroll
      for (int r = 0; r < 4; ++r) {
        int row = bm + wm + mi * 16 + (lane >> 4) * 4 + r;
        int col = bn + wn + ni * 16 + (lane & 15);
        float v = acc[mi][ni][r];
        if (bias) v += bias[col];
        if (EPI == 1) v = 0.5f * v * (1.0f + erff(v * 0.70710678118f));
        size_t o = (size_t)row * N + col;
        if (EPI == 2) outF[o] = v + resid[o];
        else outB[o] = f2bf(v);
      }
    }
  }
}

// ---------------- repack qkv -> q,k [bh][n][dh] ----------------
__global__ __launch_bounds__(256) void repack_qk(const unsigned short* __restrict__ qkv,
                                                 unsigned short* __restrict__ q,
                                                 unsigned short* __restrict__ k) {
  int idx = blockIdx.x * 256 + threadIdx.x;  // over BB*SEQL*INNERD = 2^21
  int d = idx & (INNERD - 1);
  int n = (idx >> 9) & (SEQL - 1);
  int b = idx >> 20;
  int h = d >> 6, dh = d & 63;
  size_t src = (size_t)(b * SEQL + n) * 1536 + d;
  size_t dst = ((size_t)(b * NHEADS + h) * SEQL + n) * DHH + dh;
  q[dst] = qkv[src];
  k[dst] = qkv[src + INNERD];
}

// ---------------- v -> vt [bh][dh][n] via LDS transpose ----------------
__global__ __launch_bounds__(256) void transpose_v(const unsigned short* __restrict__ qkv,
                                                   unsigned short* __restrict__ vt) {
  __shared__ unsigned short t[64][65];
  int bh = blockIdx.x;  // 16
  int nt = blockIdx.y;  // 32
  int b = bh >> 3, h = bh & 7;
  for (int i = threadIdx.x; i < 64 * 64; i += 256) {
    int n = i >> 6, dh = i & 63;
    t[n][dh] = qkv[(size_t)(b * SEQL + nt * 64 + n) * 1536 + 2 * INNERD + h * 64 + dh];
  }
  __syncthreads();
  for (int i = threadIdx.x; i < 64 * 64; i += 256) {
    int dh = i >> 6, n = i & 63;
    vt[((size_t)bh * DHH + dh) * SEQL + nt * 64 + n] = t[n][dh];
  }
}

// ---------------- flash attention, KV-split, swapped-QK^T softmax ----------------
__global__ __launch_bounds__(256, 4)
void attn_split(const unsigned short* __restrict__ qg,
                const unsigned short* __restrict__ kg,
                const unsigned short* __restrict__ vtg,
                const float* __restrict__ maskadd,
                unsigned short* __restrict__ opart,  // [NSPLIT][16][SEQL][DHH] bf16 (unnormalized)
                float* __restrict__ mlpart) {       // [NSPLIT][16][SEQL][2]
  __shared__ __align__(16) unsigned short Ks[64 * 64];
  __shared__ __align__(16) unsigned short Vts[64 * 64];
  __shared__ __align__(16) unsigned short Ps[4 * 16 * 64];
  const int tid = threadIdx.x, w = tid >> 6, lane = tid & 63;
  const int g = lane >> 4, c = lane & 15;
  const int bh = blockIdx.y, b = bh >> 3;
  const int qt = blockIdx.x;
  const int split = blockIdx.z;
  const int kv0 = split * KPS;
  const int q0 = qt * 64 + w * 16;
  const float* maskb = maskadd + b * SEQL;

  bf16x8 qf[2];
#pragma unroll
  for (int kb = 0; kb < 2; ++kb)
    qf[kb] = *(const bf16x8*)&qg[((size_t)bh * SEQL + q0 + c) * DHH + kb * 32 + g * 8];
  const float mq = maskb[q0 + c];

  float m_q = NEGF, l_q = 0.f;
  f32x4 o[4] = {};
  unsigned short* myP = &Ps[w * 1024];

  for (int kt = 0; kt < KPS / 64; ++kt) {
#pragma unroll
    for (int j = 0; j < 2; ++j) {
      int r = w * 16 + j * 8 + (lane >> 3);
      int cl = (lane & 7) ^ (r & 7);
      GLDS16(kg + ((size_t)bh * SEQL + kv0 + kt * 64 + r) * DHH + cl * 8, &Ks[(w * 16 + j * 8) * 64]);
      GLDS16(vtg + ((size_t)bh * DHH + r) * SEQL + kv0 + kt * 64 + cl * 8, &Vts[(w * 16 + j * 8) * 64]);
    }
    __syncthreads();

    // S^T = K @ Q^T : lane holds S[k = nt*16+g*4+r][q = c]
    f32x4 sT[4] = {};
#pragma unroll
    for (int nt = 0; nt < 4; ++nt) {
#pragma unroll
      for (int kb = 0; kb < 2; ++kb) {
        int kr = nt * 16 + c;
        int cs = (kb * 4 + g) ^ (kr & 7);
        bf16x8 kf = *(const bf16x8*)&Ks[kr * 64 + cs * 8];
        sT[nt] = __builtin_amdgcn_mfma_f32_16x16x32_bf16(kf, qf[kb], sT[nt], 0, 0, 0);
      }
    }

    float mx = NEGF;
#pragma unroll
    for (int nt = 0; nt < 4; ++nt) {
      f32x4 mk = *(const f32x4*)&maskb[kv0 + kt * 64 + nt * 16 + g * 4];
#pragma unroll
      for (int r = 0; r < 4; ++r) {
        float x = sT[nt][r] * SCALEF + fmaxf(mq + mk[r], NEGF);
        sT[nt][r] = x;
        mx = fmaxf(mx, x);
      }
    }
    mx = fmaxf(mx, __shfl_xor(mx, 16));
    mx = fmaxf(mx, __shfl_xor(mx, 32));
    float mn = fmaxf(m_q, mx);
    float sf = __expf(m_q - mn);
    m_q = mn;

    float rs = 0.f;
#pragma unroll
    for (int nt = 0; nt < 4; ++nt) {
      float pv0 = __expf(sT[nt][0] - mn), pv1 = __expf(sT[nt][1] - mn);
      float pv2 = __expf(sT[nt][2] - mn), pv3 = __expf(sT[nt][3] - mn);
      rs += (pv0 + pv1) + (pv2 + pv3);
      unsigned int lo = pkbf(pv0, pv1), hi = pkbf(pv2, pv3);
      int off = c * 64 + (((nt * 2 + (g >> 1)) ^ (c & 7)) << 3) + ((g & 1) << 2);
      *(uint2*)(myP + off) = make_uint2(lo, hi);
    }
    rs += __shfl_xor(rs, 16);
    rs += __shfl_xor(rs, 32);
    l_q = l_q * sf + rs;

    float sfq[4];
#pragma unroll
    for (int r = 0; r < 4; ++r) sfq[r] = __shfl(sf, g * 4 + r);
#pragma unroll
    for (int ni = 0; ni < 4; ++ni)
#pragma unroll
      for (int r = 0; r < 4; ++r) o[ni][r] *= sfq[r];

#pragma unroll
    for (int kb = 0; kb < 2; ++kb) {
      bf16x8 pf = *(const bf16x8*)&myP[c * 64 + (((kb * 4 + g) ^ (c & 7)) << 3)];
#pragma unroll
      for (int ni = 0; ni < 4; ++ni) {
        int vr = ni * 16 + c;
        int vc = (kb * 4 + g) ^ (vr & 7);
        bf16x8 vf = *(const bf16x8*)&Vts[vr * 64 + vc * 8];
        o[ni] = __builtin_amdgcn_mfma_f32_16x16x32_bf16(pf, vf, o[ni], 0, 0, 0);
      }
    }
    __syncthreads();
  }

  const size_t pb = ((size_t)split * 16 + bh) * SEQL;
#pragma unroll
  for (int ni = 0; ni < 4; ++ni)
#pragma unroll
    for (int r = 0; r < 4; ++r)
      opart[(pb + q0 + g * 4 + r) * DHH + ni * 16 + c] = f2bf(o[ni][r]);
  if (lane < 16) {
    size_t mo = (pb + q0 + lane) * 2;
    mlpart[mo] = m_q;
    mlpart[mo + 1] = l_q;
  }
}

__global__ __launch_bounds__(256) void attn_combine(const unsigned short* __restrict__ opart,
                                                    const float* __restrict__ mlpart,
                                                    unsigned short* __restrict__ ctx) {
  int idx = blockIdx.x * 256 + threadIdx.x;  // 16*SEQL*DHH = 2M
  int d = idx & 63, q = (idx >> 6) & (SEQL - 1), bh = idx >> 17;
  float m[NSPLIT], l[NSPLIT], M = NEGF;
#pragma unroll
  for (int s = 0; s < NSPLIT; ++s) {
    size_t mo = (((size_t)s * 16 + bh) * SEQL + q) * 2;
    m[s] = mlpart[mo];
    l[s] = mlpart[mo + 1];
    M = fmaxf(M, m[s]);
  }
  float L = 0.f, ov = 0.f;
#pragma unroll
  for (int s = 0; s < NSPLIT; ++s) {
    float e = __expf(m[s] - M);
    L += l[s] * e;
    ov += bf2f(opart[(((size_t)s * 16 + bh) * SEQL + q) * DHH + d]) * e;
  }
  int b = bh >> 3, h = bh & 7;
  ctx[((size_t)(b * SEQL + q)) * INNERD + h * 64 + d] = f2bf(ov / L);
}

// ---------------- host ----------------
extern "C" void kernel_launch(void* const* d_in, const int* in_sizes, int n_in,
                              void* d_out, int out_size, void* d_ws, size_t ws_size,
                              hipStream_t stream) {
  (void)in_sizes; (void)n_in; (void)out_size; (void)ws_size;
  const float* x_in = (const float*)d_in[0];
  const int* mask = (const int*)d_in[1];
  const float* qkv_w = (const float*)d_in[2];
  const float* out_w = (const float*)d_in[3];
  const float* out_b = (const float*)d_in[4];
  const float* ff_w1 = (const float*)d_in[5];
  const float* ff_b1 = (const float*)d_in[6];
  const float* ff_w2 = (const float*)d_in[7];
  const float* ff_b2 = (const float*)d_in[8];
  const float* ad1w = (const float*)d_in[9];
  const float* ad1b = (const float*)d_in[10];
  const float* ad2w = (const float*)d_in[11];
  const float* ad2b = (const float*)d_in[12];

  char* ws = (char*)d_ws;
  size_t off = 0;
  auto alloc = [&](size_t bytes) {
    char* p = ws + off;
    off = (off + bytes + 255) & ~(size_t)255;
    return p;
  };
  unsigned short* wtQ = (unsigned short*)alloc((size_t)DEPTHL * 1536 * 512 * 2);
  unsigned short* wtO = (unsigned short*)alloc((size_t)DEPTHL * 512 * 512 * 2);
  unsigned short* wtF1 = (unsigned short*)alloc((size_t)DEPTHL * 2048 * 512 * 2);
  unsigned short* wtF2 = (unsigned short*)alloc((size_t)DEPTHL * 512 * 2048 * 2);
  float* xc = (float*)alloc((size_t)ROWS * DIMM * 4);
  unsigned short* hbf = (unsigned short*)alloc((size_t)ROWS * DIMM * 2);
  unsigned short* qkvbf = (unsigned short*)alloc((size_t)ROWS * 1536 * 2);
  char* region2 = alloc((size_t)4 * 16 * SEQL * DHH * 2);  // q,k,vt,ctx OR h1
  unsigned short* qb = (unsigned short*)region2;
  unsigned short* kb = qb + (size_t)16 * SEQL * DHH;
  unsigned short* vtb = kb + (size_t)16 * SEQL * DHH;
  unsigned short* ctxb = vtb + (size_t)16 * SEQL * DHH;
  unsigned short* h1bf = (unsigned short*)region2;  // aliases q/k/vt/ctx (disjoint lifetime)
  float* p1 = (float*)alloc((size_t)BB * 32 * DIMM * 4);
  float* p2 = (float*)alloc((size_t)BB * 32 * DIMM * 4);
  float* alpha = (float*)alloc((size_t)BB * DIMM * 4);
  float* beta = (float*)alloc((size_t)BB * DIMM * 4);
  float* maskadd = (float*)alloc((size_t)BB * SEQL * 4);
  unsigned short* opart = (unsigned short*)alloc((size_t)NSPLIT * 16 * SEQL * DHH * 2);
  float* mlpart = (float*)alloc((size_t)NSPLIT * 16 * SEQL * 2 * 4);

  // x working copy
  hipMemcpyAsync(xc, x_in, (size_t)ROWS * DIMM * 4, hipMemcpyDeviceToDevice, stream);

  // weights -> bf16 transposed [N][K]
  wtrans<<<dim3(512 / 32, 1536 / 32, DEPTHL), 256, 0, stream>>>(qkv_w, wtQ, 512, 1536);
  wtrans<<<dim3(512 / 32, 512 / 32, DEPTHL), 256, 0, stream>>>(out_w, wtO, 512, 512);
  wtrans<<<dim3(512 / 32, 2048 / 32, DEPTHL), 256, 0, stream>>>(ff_w1, wtF1, 512, 2048);
  wtrans<<<dim3(2048 / 32, 512 / 32, DEPTHL), 256, 0, stream>>>(ff_w2, wtF2, 2048, 512);
  maskbuild<<<BB * SEQL / 256, 256, 0, stream>>>(mask, maskadd);

  for (int l = 0; l < DEPTHL; ++l) {
    // adain 1
    adain_p1<<<dim3(32, BB), 512, 0, stream>>>(xc, p1, p2);
    adain_p2<<<BB, 512, 0, stream>>>(p1, p2, ad1w + l * BB * DIMM, ad1b + l * BB * DIMM, alpha, beta);
    adain_apply<<<8192, 256, 0, stream>>>(xc, alpha, beta, hbf);
    // qkv
    gemm_k<0><<<dim3(1536 / 128, ROWS / 128), 256, 0, stream>>>(
        hbf, wtQ + (size_t)l * 1536 * 512, nullptr, nullptr, nullptr, qkvbf, 1536, 512);
    repack_qk<<<8192, 256, 0, stream>>>(qkvbf, qb, kb);
    transpose_v<<<dim3(16, 32), 256, 0, stream>>>(qkvbf, vtb);
    attn_split<<<dim3(SEQL / 64, 16, NSPLIT), 256, 0, stream>>>(qb, kb, vtb, maskadd, opart, mlpart);
    attn_combine<<<16 * SEQL * DHH / 256, 256, 0, stream>>>(opart, mlpart, ctxb);
    // out proj + residual (in place on xc)
    gemm_k<2><<<dim3(512 / 128, ROWS / 128), 256, 0, stream>>>(
        ctxb, wtO + (size_t)l * 512 * 512, out_b + l * DIMM, xc, xc, nullptr, 512, 512);
    // adain 2
    adain_p1<<<dim3(32, BB), 512, 0, stream>>>(xc, p1, p2);
    adain_p2<<<BB, 512, 0, stream>>>(p1, p2, ad2w + l * BB * DIMM, ad2b + l * BB * DIMM, alpha, beta);
    adain_apply<<<8192, 256, 0, stream>>>(xc, alpha, beta, hbf);
    // ff1 (gelu) -> h1
    gemm_k<1><<<dim3(2048 / 128, ROWS / 128), 256, 0, stream>>>(
        hbf, wtF1 + (size_t)l * 2048 * 512, ff_b1 + l * MLPD, nullptr, nullptr, h1bf, 2048, 512);
    // ff2 + residual
    float* xout = (l == DEPTHL - 1) ? (float*)d_out : xc;
    gemm_k<2><<<dim3(512 / 128, ROWS / 128), 256, 0, stream>>>(
        h1bf, wtF2 + (size_t)l * 512 * 2048, ff_b2 + l * DIMM, xc, xout, nullptr, 512, 2048);
  }
}

// Round 4
// 357.409 us; speedup vs baseline: 1.5161x; 1.3304x over previous
//
#include <hip/hip_runtime.h>
#include <hip/hip_bf16.h>

#define DEPTHL 2
#define DIMM   512
#define NHEADS 8
#define DHH    64
#define INNERD 512
#define MLPD   2048
#define BB     2
#define SEQL   2048
#define ROWS   (BB*SEQL)
#define NEGF   (-3.402823466e38f)
#define SCALEF 0.125f
#define NSPLIT 4
#define KPS    (SEQL / NSPLIT)

typedef __attribute__((ext_vector_type(4))) float f32x4;
typedef __attribute__((ext_vector_type(8))) __bf16 bf16x8;

#define GLDS16(g, l) __builtin_amdgcn_global_load_lds((const __attribute__((address_space(1))) void*)(g), (__attribute__((address_space(3))) void*)(l), 16, 0, 0)

__device__ __forceinline__ unsigned short f2bf(float f) {
  union { float f; unsigned int u; } v; v.f = f;
  unsigned int r = v.u + 0x7fffu + ((v.u >> 16) & 1u);
  return (unsigned short)(r >> 16);
}
__device__ __forceinline__ float bf2f(unsigned short h) {
  union { unsigned int u; float f; } v; v.u = ((unsigned int)h) << 16; return v.f;
}
__device__ __forceinline__ unsigned int pkbf(float a, float b) {
  return (unsigned int)f2bf(a) | ((unsigned int)f2bf(b) << 16);
}

// ---------------- weight transpose fp32[K][N] -> bf16[N][K] ----------------
__global__ __launch_bounds__(256) void wtrans(const float* __restrict__ wsrc,
                                              unsigned short* __restrict__ wdst,
                                              int K, int N) {
  __shared__ float t[32][33];
  const float* src = wsrc + (size_t)blockIdx.z * K * N;
  unsigned short* dst = wdst + (size_t)blockIdx.z * K * N;
  int k0 = blockIdx.x * 32, n0 = blockIdx.y * 32;
  int tx = threadIdx.x & 31, ty = threadIdx.x >> 5;  // 32x8
#pragma unroll
  for (int j = 0; j < 32; j += 8)
    t[ty + j][tx] = src[(size_t)(k0 + ty + j) * N + n0 + tx];
  __syncthreads();
#pragma unroll
  for (int j = 0; j < 32; j += 8)
    dst[(size_t)(n0 + ty + j) * K + k0 + tx] = f2bf(t[tx][ty + j]);
}

// ---------------- adain ----------------
__global__ __launch_bounds__(512) void adain_p1(const float* __restrict__ x,
                                                float* __restrict__ p1, float* __restrict__ p2) {
  int d = threadIdx.x, c = blockIdx.x, b = blockIdx.y;
  const float* xp = x + ((size_t)b * SEQL + c * 64) * DIMM + d;
  float s = 0.f, s2 = 0.f;
  for (int i = 0; i < 64; ++i) { float v = xp[(size_t)i * DIMM]; s += v; s2 += v * v; }
  p1[(b * 32 + c) * DIMM + d] = s;
  p2[(b * 32 + c) * DIMM + d] = s2;
}

__global__ __launch_bounds__(512) void adain_p2(const float* __restrict__ p1, const float* __restrict__ p2,
                                                const float* __restrict__ w, const float* __restrict__ bi,
                                                float* __restrict__ alpha, float* __restrict__ beta) {
  int d = threadIdx.x, b = blockIdx.x;
  float s = 0.f, s2 = 0.f;
  for (int c = 0; c < 32; ++c) { s += p1[(b * 32 + c) * DIMM + d]; s2 += p2[(b * 32 + c) * DIMM + d]; }
  float mean = s * (1.0f / SEQL);
  float var = s2 * (1.0f / SEQL) - mean * mean;
  float a = w[b * DIMM + d] * rsqrtf(var + 1e-6f);
  alpha[b * DIMM + d] = a;
  beta[b * DIMM + d] = bi[b * DIMM + d] - mean * a;
}

__global__ __launch_bounds__(256) void adain_apply(const float* __restrict__ x,
                                                   const float* __restrict__ alpha, const float* __restrict__ beta,
                                                   unsigned short* __restrict__ hb) {
  int idx = blockIdx.x * 256 + threadIdx.x;  // over ROWS*DIMM = 2^21
  int d = idx & (DIMM - 1);
  int b = idx >> 20;  // SEQL*DIMM = 2^20
  hb[idx] = f2bf(x[idx] * alpha[b * DIMM + d] + beta[b * DIMM + d]);
}

// ---------------- mask -> additive float ----------------
__global__ __launch_bounds__(256) void maskbuild(const int* __restrict__ mask, float* __restrict__ maskadd) {
  int i = blockIdx.x * 256 + threadIdx.x;  // B*N = 4096
  maskadd[i] = mask[i] ? 0.f : NEGF;
}

// ---------------- GEMM: out = A[M,Kt](bf16) @ Wt[N,Kt]^T(bf16) ----------------
// EPI: 0 = bf16 out, 1 = gelu->bf16 out, 2 = fp32 out + bias + resid, 3 = fp32 partial (split-K)
// BN: N tile (64 or 128). 2-phase dbuf + XCD-chunked remap (gridDim.y must be %8... rpx computed).
template <int EPI, int BN>
__global__ __launch_bounds__(256)
void gemm_k(const unsigned short* __restrict__ A,
            const unsigned short* __restrict__ Wt,
            const float* __restrict__ bias,
            const float* __restrict__ resid,
            float* __restrict__ outF,
            unsigned short* __restrict__ outB,
            float* __restrict__ part,
            int N, int Kt) {
  constexpr int NI = BN / 32;  // B frags / acc cols per wave
  __shared__ __align__(16) unsigned short As[2][128 * 32];
  __shared__ __align__(16) unsigned short Bs[2][BN * 32];
  const int tid = threadIdx.x;
  const int w = tid >> 6, lane = tid & 63;

  // XCD-aware remap within each z-slice
  unsigned int f = blockIdx.y * gridDim.x + blockIdx.x;
  unsigned int grp = f & 7u, idx = f >> 3;
  unsigned int rpx = gridDim.y >> 3;
  unsigned int by = grp * rpx + idx / gridDim.x;
  unsigned int bx = idx % gridDim.x;

  const int bm = by * 128, bn = bx * BN;
  const int wm = (w >> 1) * 64, wn = (w & 1) * (BN / 2);

  // split-K range
  const int nsplit = gridDim.z, sp = blockIdx.z;
  const int Kc = Kt / nsplit;
  const int kbeg = sp * Kc, kend = kbeg + Kc;

  f32x4 acc[4][NI] = {};

  auto stage = [&](int buf, int k0) {
#pragma unroll
    for (int j = 0; j < 2; ++j) {
      int r = w * 32 + (lane >> 2) + j * 16;
      int cl = (lane & 3) ^ ((r >> 1) & 3);
      GLDS16(A + (size_t)(bm + r) * Kt + k0 + cl * 8, &As[buf][(w * 32 + j * 16) * 32]);
    }
    if (BN == 128) {
#pragma unroll
      for (int j = 0; j < 2; ++j) {
        int r = w * 32 + (lane >> 2) + j * 16;
        int cl = (lane & 3) ^ ((r >> 1) & 3);
        GLDS16(Wt + (size_t)(bn + r) * Kt + k0 + cl * 8, &Bs[buf][(w * 32 + j * 16) * 32]);
      }
    } else {
      int r = w * 16 + (lane >> 2);
      int cl = (lane & 3) ^ ((r >> 1) & 3);
      GLDS16(Wt + (size_t)(bn + r) * Kt + k0 + cl * 8, &Bs[buf][(w * 16) * 32]);
    }
  };

  stage(0, kbeg);
  __syncthreads();
  int cur = 0;

  for (int k0 = kbeg; k0 < kend; k0 += 32) {
    if (k0 + 32 < kend) stage(cur ^ 1, k0 + 32);
    bf16x8 af[4], bfr[NI];
#pragma unroll
    for (int i = 0; i < 4; ++i) {
      int ar = wm + i * 16 + (lane & 15);
      int ac = (lane >> 4) ^ ((ar >> 1) & 3);
      af[i] = *(const bf16x8*)&As[cur][ar * 32 + ac * 8];
    }
#pragma unroll
    for (int i = 0; i < NI; ++i) {
      int br = wn + i * 16 + (lane & 15);
      int bc = (lane >> 4) ^ ((br >> 1) & 3);
      bfr[i] = *(const bf16x8*)&Bs[cur][br * 32 + bc * 8];
    }
#pragma unroll
    for (int mi = 0; mi < 4; ++mi)
#pragma unroll
      for (int ni = 0; ni < NI; ++ni)
        acc[mi][ni] = __builtin_amdgcn_mfma_f32_16x16x32_bf16(af[mi], bfr[ni], acc[mi][ni], 0, 0, 0);
    __syncthreads();
    cur ^= 1;
  }

  const size_t MN = (size_t)gridDim.y * 128 * N;
#pragma unroll
  for (int mi = 0; mi < 4; ++mi) {
#pragma unroll
    for (int ni = 0; ni < NI; ++ni) {
#pragma unroll
      for (int r = 0; r < 4; ++r) {
        int row = bm + wm + mi * 16 + (lane >> 4) * 4 + r;
        int col = bn + wn + ni * 16 + (lane & 15);
        float v = acc[mi][ni][r];
        size_t o = (size_t)row * N + col;
        if (EPI == 3) {
          part[(size_t)sp * MN + o] = v;
        } else {
          if (bias) v += bias[col];
          if (EPI == 1) v = 0.5f * v * (1.0f + erff(v * 0.70710678118f));
          if (EPI == 2) outF[o] = v + resid[o];
          else if (EPI != 2) outB[o] = f2bf(v);
        }
      }
    }
  }
}

// ---------------- split-K combine: out = sum(part) + bias + resid (N = 512 fixed) ----------------
template <int NS>
__global__ __launch_bounds__(256) void comb_k(const float* __restrict__ part,
                                              const float* __restrict__ bias,
                                              const float* __restrict__ resid,
                                              float* __restrict__ outF) {
  size_t idx = ((size_t)blockIdx.x * 256 + threadIdx.x) * 4;  // over ROWS*512
  int col = (int)(idx & 511);
  f32x4 v = *(const f32x4*)&part[idx];
#pragma unroll
  for (int s = 1; s < NS; ++s)
    v += *(const f32x4*)&part[(size_t)s * ROWS * 512 + idx];
  v += *(const f32x4*)&bias[col];
  v += *(const f32x4*)&resid[idx];
  *(f32x4*)&outF[idx] = v;
}

// ---------------- repack qkv -> q,k [bh][n][dh] ----------------
__global__ __launch_bounds__(256) void repack_qk(const unsigned short* __restrict__ qkv,
                                                 unsigned short* __restrict__ q,
                                                 unsigned short* __restrict__ k) {
  int idx = blockIdx.x * 256 + threadIdx.x;  // over BB*SEQL*INNERD = 2^21
  int d = idx & (INNERD - 1);
  int n = (idx >> 9) & (SEQL - 1);
  int b = idx >> 20;
  int h = d >> 6, dh = d & 63;
  size_t src = (size_t)(b * SEQL + n) * 1536 + d;
  size_t dst = ((size_t)(b * NHEADS + h) * SEQL + n) * DHH + dh;
  q[dst] = qkv[src];
  k[dst] = qkv[src + INNERD];
}

// ---------------- v -> vt [bh][dh][n] via LDS transpose ----------------
__global__ __launch_bounds__(256) void transpose_v(const unsigned short* __restrict__ qkv,
                                                   unsigned short* __restrict__ vt) {
  __shared__ unsigned short t[64][65];
  int bh = blockIdx.x;  // 16
  int nt = blockIdx.y;  // 32
  int b = bh >> 3, h = bh & 7;
  for (int i = threadIdx.x; i < 64 * 64; i += 256) {
    int n = i >> 6, dh = i & 63;
    t[n][dh] = qkv[(size_t)(b * SEQL + nt * 64 + n) * 1536 + 2 * INNERD + h * 64 + dh];
  }
  __syncthreads();
  for (int i = threadIdx.x; i < 64 * 64; i += 256) {
    int dh = i >> 6, n = i & 63;
    vt[((size_t)bh * DHH + dh) * SEQL + nt * 64 + n] = t[n][dh];
  }
}

// ---------------- flash attention, KV-split, swapped-QK^T softmax ----------------
__global__ __launch_bounds__(256, 4)
void attn_split(const unsigned short* __restrict__ qg,
                const unsigned short* __restrict__ kg,
                const unsigned short* __restrict__ vtg,
                const float* __restrict__ maskadd,
                unsigned short* __restrict__ opart,  // [NSPLIT][16][SEQL][DHH] bf16 (unnormalized)
                float* __restrict__ mlpart) {       // [NSPLIT][16][SEQL][2]
  __shared__ __align__(16) unsigned short Ks[64 * 64];
  __shared__ __align__(16) unsigned short Vts[64 * 64];
  __shared__ __align__(16) unsigned short Ps[4 * 16 * 64];
  const int tid = threadIdx.x, w = tid >> 6, lane = tid & 63;
  const int g = lane >> 4, c = lane & 15;
  const int bh = blockIdx.y, b = bh >> 3;
  const int qt = blockIdx.x;
  const int split = blockIdx.z;
  const int kv0 = split * KPS;
  const int q0 = qt * 64 + w * 16;
  const float* maskb = maskadd + b * SEQL;

  bf16x8 qf[2];
#pragma unroll
  for (int kb = 0; kb < 2; ++kb)
    qf[kb] = *(const bf16x8*)&qg[((size_t)bh * SEQL + q0 + c) * DHH + kb * 32 + g * 8];
  const float mq = maskb[q0 + c];

  float m_q = NEGF, l_q = 0.f;
  f32x4 o[4] = {};
  unsigned short* myP = &Ps[w * 1024];

  for (int kt = 0; kt < KPS / 64; ++kt) {
#pragma unroll
    for (int j = 0; j < 2; ++j) {
      int r = w * 16 + j * 8 + (lane >> 3);
      int cl = (lane & 7) ^ (r & 7);
      GLDS16(kg + ((size_t)bh * SEQL + kv0 + kt * 64 + r) * DHH + cl * 8, &Ks[(w * 16 + j * 8) * 64]);
      GLDS16(vtg + ((size_t)bh * DHH + r) * SEQL + kv0 + kt * 64 + cl * 8, &Vts[(w * 16 + j * 8) * 64]);
    }
    __syncthreads();

    // S^T = K @ Q^T : lane holds S[k = nt*16+g*4+r][q = c]
    f32x4 sT[4] = {};
#pragma unroll
    for (int nt = 0; nt < 4; ++nt) {
#pragma unroll
      for (int kb = 0; kb < 2; ++kb) {
        int kr = nt * 16 + c;
        int cs = (kb * 4 + g) ^ (kr & 7);
        bf16x8 kf = *(const bf16x8*)&Ks[kr * 64 + cs * 8];
        sT[nt] = __builtin_amdgcn_mfma_f32_16x16x32_bf16(kf, qf[kb], sT[nt], 0, 0, 0);
      }
    }

    float mx = NEGF;
#pragma unroll
    for (int nt = 0; nt < 4; ++nt) {
      f32x4 mk = *(const f32x4*)&maskb[kv0 + kt * 64 + nt * 16 + g * 4];
#pragma unroll
      for (int r = 0; r < 4; ++r) {
        float x = sT[nt][r] * SCALEF + fmaxf(mq + mk[r], NEGF);
        sT[nt][r] = x;
        mx = fmaxf(mx, x);
      }
    }
    mx = fmaxf(mx, __shfl_xor(mx, 16));
    mx = fmaxf(mx, __shfl_xor(mx, 32));
    float mn = fmaxf(m_q, mx);
    float sf = __expf(m_q - mn);
    m_q = mn;

    float rs = 0.f;
#pragma unroll
    for (int nt = 0; nt < 4; ++nt) {
      float pv0 = __expf(sT[nt][0] - mn), pv1 = __expf(sT[nt][1] - mn);
      float pv2 = __expf(sT[nt][2] - mn), pv3 = __expf(sT[nt][3] - mn);
      rs += (pv0 + pv1) + (pv2 + pv3);
      unsigned int lo = pkbf(pv0, pv1), hi = pkbf(pv2, pv3);
      int off = c * 64 + (((nt * 2 + (g >> 1)) ^ (c & 7)) << 3) + ((g & 1) << 2);
      *(uint2*)(myP + off) = make_uint2(lo, hi);
    }
    rs += __shfl_xor(rs, 16);
    rs += __shfl_xor(rs, 32);
    l_q = l_q * sf + rs;

    float sfq[4];
#pragma unroll
    for (int r = 0; r < 4; ++r) sfq[r] = __shfl(sf, g * 4 + r);
#pragma unroll
    for (int ni = 0; ni < 4; ++ni)
#pragma unroll
      for (int r = 0; r < 4; ++r) o[ni][r] *= sfq[r];

#pragma unroll
    for (int kb = 0; kb < 2; ++kb) {
      bf16x8 pf = *(const bf16x8*)&myP[c * 64 + (((kb * 4 + g) ^ (c & 7)) << 3)];
#pragma unroll
      for (int ni = 0; ni < 4; ++ni) {
        int vr = ni * 16 + c;
        int vc = (kb * 4 + g) ^ (vr & 7);
        bf16x8 vf = *(const bf16x8*)&Vts[vr * 64 + vc * 8];
        o[ni] = __builtin_amdgcn_mfma_f32_16x16x32_bf16(pf, vf, o[ni], 0, 0, 0);
      }
    }
    __syncthreads();
  }

  const size_t pb = ((size_t)split * 16 + bh) * SEQL;
#pragma unroll
  for (int ni = 0; ni < 4; ++ni)
#pragma unroll
    for (int r = 0; r < 4; ++r)
      opart[(pb + q0 + g * 4 + r) * DHH + ni * 16 + c] = f2bf(o[ni][r]);
  if (lane < 16) {
    size_t mo = (pb + q0 + lane) * 2;
    mlpart[mo] = m_q;
    mlpart[mo + 1] = l_q;
  }
}

__global__ __launch_bounds__(256) void attn_combine(const unsigned short* __restrict__ opart,
                                                    const float* __restrict__ mlpart,
                                                    unsigned short* __restrict__ ctx) {
  int idx = blockIdx.x * 256 + threadIdx.x;  // 16*SEQL*DHH = 2M
  int d = idx & 63, q = (idx >> 6) & (SEQL - 1), bh = idx >> 17;
  float m[NSPLIT], l[NSPLIT], M = NEGF;
#pragma unroll
  for (int s = 0; s < NSPLIT; ++s) {
    size_t mo = (((size_t)s * 16 + bh) * SEQL + q) * 2;
    m[s] = mlpart[mo];
    l[s] = mlpart[mo + 1];
    M = fmaxf(M, m[s]);
  }
  float L = 0.f, ov = 0.f;
#pragma unroll
  for (int s = 0; s < NSPLIT; ++s) {
    float e = __expf(m[s] - M);
    L += l[s] * e;
    ov += bf2f(opart[(((size_t)s * 16 + bh) * SEQL + q) * DHH + d]) * e;
  }
  int b = bh >> 3, h = bh & 7;
  ctx[((size_t)(b * SEQL + q)) * INNERD + h * 64 + d] = f2bf(ov / L);
}

// ---------------- host ----------------
extern "C" void kernel_launch(void* const* d_in, const int* in_sizes, int n_in,
                              void* d_out, int out_size, void* d_ws, size_t ws_size,
                              hipStream_t stream) {
  (void)in_sizes; (void)n_in; (void)out_size;
  const float* x_in = (const float*)d_in[0];
  const int* mask = (const int*)d_in[1];
  const float* qkv_w = (const float*)d_in[2];
  const float* out_w = (const float*)d_in[3];
  const float* out_b = (const float*)d_in[4];
  const float* ff_w1 = (const float*)d_in[5];
  const float* ff_b1 = (const float*)d_in[6];
  const float* ff_w2 = (const float*)d_in[7];
  const float* ff_b2 = (const float*)d_in[8];
  const float* ad1w = (const float*)d_in[9];
  const float* ad1b = (const float*)d_in[10];
  const float* ad2w = (const float*)d_in[11];
  const float* ad2b = (const float*)d_in[12];

  char* ws = (char*)d_ws;
  size_t off = 0;
  auto alloc = [&](size_t bytes) {
    char* p = ws + off;
    off = (off + bytes + 255) & ~(size_t)255;
    return p;
  };
  unsigned short* wtQ = (unsigned short*)alloc((size_t)DEPTHL * 1536 * 512 * 2);
  unsigned short* wtO = (unsigned short*)alloc((size_t)DEPTHL * 512 * 512 * 2);
  unsigned short* wtF1 = (unsigned short*)alloc((size_t)DEPTHL * 2048 * 512 * 2);
  unsigned short* wtF2 = (unsigned short*)alloc((size_t)DEPTHL * 512 * 2048 * 2);
  float* xc = (float*)alloc((size_t)ROWS * DIMM * 4);
  unsigned short* hbf = (unsigned short*)alloc((size_t)ROWS * DIMM * 2);
  unsigned short* qkvbf = (unsigned short*)alloc((size_t)ROWS * 1536 * 2);
  char* region2 = alloc((size_t)4 * 16 * SEQL * DHH * 2);  // q,k,vt,ctx OR h1
  unsigned short* qb = (unsigned short*)region2;
  unsigned short* kb = qb + (size_t)16 * SEQL * DHH;
  unsigned short* vtb = kb + (size_t)16 * SEQL * DHH;
  unsigned short* ctxb = vtb + (size_t)16 * SEQL * DHH;
  unsigned short* h1bf = (unsigned short*)region2;  // aliases q/k/vt/ctx (disjoint lifetime)
  float* p1 = (float*)alloc((size_t)BB * 32 * DIMM * 4);
  float* p2 = (float*)alloc((size_t)BB * 32 * DIMM * 4);
  float* alpha = (float*)alloc((size_t)BB * DIMM * 4);
  float* beta = (float*)alloc((size_t)BB * DIMM * 4);
  float* maskadd = (float*)alloc((size_t)BB * SEQL * 4);
  unsigned short* opart = (unsigned short*)alloc((size_t)NSPLIT * 16 * SEQL * DHH * 2);
  float* mlpart = (float*)alloc((size_t)NSPLIT * 16 * SEQL * 2 * 4);
  float* part = (float*)alloc((size_t)4 * ROWS * 512 * 4);  // 32MB split-K partials
  const bool fits = off <= ws_size;  // graceful fallback if workspace too small

  // x working copy
  hipMemcpyAsync(xc, x_in, (size_t)ROWS * DIMM * 4, hipMemcpyDeviceToDevice, stream);

  // weights -> bf16 transposed [N][K]
  wtrans<<<dim3(512 / 32, 1536 / 32, DEPTHL), 256, 0, stream>>>(qkv_w, wtQ, 512, 1536);
  wtrans<<<dim3(512 / 32, 512 / 32, DEPTHL), 256, 0, stream>>>(out_w, wtO, 512, 512);
  wtrans<<<dim3(512 / 32, 2048 / 32, DEPTHL), 256, 0, stream>>>(ff_w1, wtF1, 512, 2048);
  wtrans<<<dim3(2048 / 32, 512 / 32, DEPTHL), 256, 0, stream>>>(ff_w2, wtF2, 2048, 512);
  maskbuild<<<BB * SEQL / 256, 256, 0, stream>>>(mask, maskadd);

  for (int l = 0; l < DEPTHL; ++l) {
    // adain 1
    adain_p1<<<dim3(32, BB), 512, 0, stream>>>(xc, p1, p2);
    adain_p2<<<BB, 512, 0, stream>>>(p1, p2, ad1w + l * BB * DIMM, ad1b + l * BB * DIMM, alpha, beta);
    adain_apply<<<8192, 256, 0, stream>>>(xc, alpha, beta, hbf);
    // qkv: [4096,512] x [512,1536] -> bf16
    gemm_k<0, 64><<<dim3(1536 / 64, ROWS / 128), 256, 0, stream>>>(
        hbf, wtQ + (size_t)l * 1536 * 512, nullptr, nullptr, nullptr, qkvbf, nullptr, 1536, 512);
    repack_qk<<<8192, 256, 0, stream>>>(qkvbf, qb, kb);
    transpose_v<<<dim3(16, 32), 256, 0, stream>>>(qkvbf, vtb);
    attn_split<<<dim3(SEQL / 64, 16, NSPLIT), 256, 0, stream>>>(qb, kb, vtb, maskadd, opart, mlpart);
    attn_combine<<<16 * SEQL * DHH / 256, 256, 0, stream>>>(opart, mlpart, ctxb);
    // out proj + residual (in place on xc)
    if (fits) {
      gemm_k<3, 64><<<dim3(512 / 64, ROWS / 128, 2), 256, 0, stream>>>(
          ctxb, wtO + (size_t)l * 512 * 512, nullptr, nullptr, nullptr, nullptr, part, 512, 512);
      comb_k<2><<<ROWS * 512 / 1024, 256, 0, stream>>>(part, out_b + l * DIMM, xc, xc);
    } else {
      gemm_k<2, 64><<<dim3(512 / 64, ROWS / 128), 256, 0, stream>>>(
          ctxb, wtO + (size_t)l * 512 * 512, out_b + l * DIMM, xc, xc, nullptr, nullptr, 512, 512);
    }
    // adain 2
    adain_p1<<<dim3(32, BB), 512, 0, stream>>>(xc, p1, p2);
    adain_p2<<<BB, 512, 0, stream>>>(p1, p2, ad2w + l * BB * DIMM, ad2b + l * BB * DIMM, alpha, beta);
    adain_apply<<<8192, 256, 0, stream>>>(xc, alpha, beta, hbf);
    // ff1 (gelu) -> h1
    gemm_k<1, 64><<<dim3(2048 / 64, ROWS / 128), 256, 0, stream>>>(
        hbf, wtF1 + (size_t)l * 2048 * 512, ff_b1 + l * MLPD, nullptr, nullptr, h1bf, nullptr, 2048, 512);
    // ff2 + residual
    float* xout = (l == DEPTHL - 1) ? (float*)d_out : xc;
    if (fits) {
      gemm_k<3, 64><<<dim3(512 / 64, ROWS / 128, 4), 256, 0, stream>>>(
          h1bf, wtF2 + (size_t)l * 512 * 2048, nullptr, nullptr, nullptr, nullptr, part, 512, 2048);
      comb_k<4><<<ROWS * 512 / 1024, 256, 0, stream>>>(part, ff_b2 + l * DIMM, xc, xout);
    } else {
      gemm_k<2, 64><<<dim3(512 / 64, ROWS / 128), 256, 0, stream>>>(
          h1bf, wtF2 + (size_t)l * 512 * 2048, ff_b2 + l * DIMM, xc, xout, nullptr, nullptr, 512, 2048);
    }
  }
}

// Round 5
// 352.643 us; speedup vs baseline: 1.5366x; 1.0135x over previous
//
#include <hip/hip_runtime.h>
#include <hip/hip_bf16.h>

#define DEPTHL 2
#define DIMM   512
#define NHEADS 8
#define DHH    64
#define INNERD 512
#define MLPD   2048
#define BB     2
#define SEQL   2048
#define ROWS   (BB*SEQL)
#define NEGF   (-3.402823466e38f)
#define MNEG   (-1.0e38f)
#define SCL2   (0.125f * 1.44269504088896340736f)
#define NSPLIT 4
#define KPS    (SEQL / NSPLIT)

typedef __attribute__((ext_vector_type(4))) float f32x4;
typedef __attribute__((ext_vector_type(8))) __bf16 bf16x8;

#define GLDS16(g, l) __builtin_amdgcn_global_load_lds((const __attribute__((address_space(1))) void*)(g), (__attribute__((address_space(3))) void*)(l), 16, 0, 0)

__device__ __forceinline__ unsigned short f2bf(float f) {
  union { float f; unsigned int u; } v; v.f = f;
  unsigned int r = v.u + 0x7fffu + ((v.u >> 16) & 1u);
  return (unsigned short)(r >> 16);
}
__device__ __forceinline__ float bf2f(unsigned short h) {
  union { unsigned int u; float f; } v; v.u = ((unsigned int)h) << 16; return v.f;
}
// packed RNE f32x2 -> bf16x2 (T12 primitive; no builtin on gfx950)
__device__ __forceinline__ unsigned int cvtpk(float a, float b) {
  unsigned int r;
  asm("v_cvt_pk_bf16_f32 %0, %1, %2" : "=v"(r) : "v"(a), "v"(b));
  return r;
}

// ---------------- weight transpose fp32[K][N] -> bf16[N][K] ----------------
__global__ __launch_bounds__(256) void wtrans(const float* __restrict__ wsrc,
                                              unsigned short* __restrict__ wdst,
                                              int K, int N) {
  __shared__ float t[32][33];
  const float* src = wsrc + (size_t)blockIdx.z * K * N;
  unsigned short* dst = wdst + (size_t)blockIdx.z * K * N;
  int k0 = blockIdx.x * 32, n0 = blockIdx.y * 32;
  int tx = threadIdx.x & 31, ty = threadIdx.x >> 5;  // 32x8
#pragma unroll
  for (int j = 0; j < 32; j += 8)
    t[ty + j][tx] = src[(size_t)(k0 + ty + j) * N + n0 + tx];
  __syncthreads();
#pragma unroll
  for (int j = 0; j < 32; j += 8)
    dst[(size_t)(n0 + ty + j) * K + k0 + tx] = f2bf(t[tx][ty + j]);
}

// ---------------- adain ----------------
__global__ __launch_bounds__(512) void adain_p1(const float* __restrict__ x,
                                                float* __restrict__ p1, float* __restrict__ p2) {
  int d = threadIdx.x, c = blockIdx.x, b = blockIdx.y;
  const float* xp = x + ((size_t)b * SEQL + c * 64) * DIMM + d;
  float s = 0.f, s2 = 0.f;
  for (int i = 0; i < 64; ++i) { float v = xp[(size_t)i * DIMM]; s += v; s2 += v * v; }
  p1[(b * 32 + c) * DIMM + d] = s;
  p2[(b * 32 + c) * DIMM + d] = s2;
}

__global__ __launch_bounds__(512) void adain_p2(const float* __restrict__ p1, const float* __restrict__ p2,
                                                const float* __restrict__ w, const float* __restrict__ bi,
                                                float* __restrict__ alpha, float* __restrict__ beta) {
  int d = threadIdx.x, b = blockIdx.x;
  float s = 0.f, s2 = 0.f;
  for (int c = 0; c < 32; ++c) { s += p1[(b * 32 + c) * DIMM + d]; s2 += p2[(b * 32 + c) * DIMM + d]; }
  float mean = s * (1.0f / SEQL);
  float var = s2 * (1.0f / SEQL) - mean * mean;
  float a = w[b * DIMM + d] * rsqrtf(var + 1e-6f);
  alpha[b * DIMM + d] = a;
  beta[b * DIMM + d] = bi[b * DIMM + d] - mean * a;
}

__global__ __launch_bounds__(256) void adain_apply(const float* __restrict__ x,
                                                   const float* __restrict__ alpha, const float* __restrict__ beta,
                                                   unsigned short* __restrict__ hb) {
  int idx = blockIdx.x * 256 + threadIdx.x;  // over ROWS*DIMM = 2^21
  int d = idx & (DIMM - 1);
  int b = idx >> 20;  // SEQL*DIMM = 2^20
  hb[idx] = f2bf(x[idx] * alpha[b * DIMM + d] + beta[b * DIMM + d]);
}

// ---------------- mask -> additive float (log2-domain; finite so sums stay finite) ----------------
__global__ __launch_bounds__(256) void maskbuild(const int* __restrict__ mask, float* __restrict__ maskadd) {
  int i = blockIdx.x * 256 + threadIdx.x;  // B*N = 4096
  maskadd[i] = mask[i] ? 0.f : MNEG;
}

// ---------------- GEMM: out = A[M,Kt](bf16) @ Wt[N,Kt]^T(bf16) ----------------
// EPI: 0 = bf16 out, 1 = gelu->bf16 out, 2 = fp32 out + bias + resid, 3 = fp32 partial (split-K)
template <int EPI, int BN>
__global__ __launch_bounds__(256)
void gemm_k(const unsigned short* __restrict__ A,
            const unsigned short* __restrict__ Wt,
            const float* __restrict__ bias,
            const float* __restrict__ resid,
            float* __restrict__ outF,
            unsigned short* __restrict__ outB,
            float* __restrict__ part,
            int N, int Kt) {
  constexpr int NI = BN / 32;  // B frags / acc cols per wave
  __shared__ __align__(16) unsigned short As[2][128 * 32];
  __shared__ __align__(16) unsigned short Bs[2][BN * 32];
  const int tid = threadIdx.x;
  const int w = tid >> 6, lane = tid & 63;

  // XCD-aware remap within each z-slice
  unsigned int f = blockIdx.y * gridDim.x + blockIdx.x;
  unsigned int grp = f & 7u, idx = f >> 3;
  unsigned int rpx = gridDim.y >> 3;
  unsigned int by = grp * rpx + idx / gridDim.x;
  unsigned int bx = idx % gridDim.x;

  const int bm = by * 128, bn = bx * BN;
  const int wm = (w >> 1) * 64, wn = (w & 1) * (BN / 2);

  // split-K range
  const int nsplit = gridDim.z, sp = blockIdx.z;
  const int Kc = Kt / nsplit;
  const int kbeg = sp * Kc, kend = kbeg + Kc;

  f32x4 acc[4][NI] = {};

  auto stage = [&](int buf, int k0) {
#pragma unroll
    for (int j = 0; j < 2; ++j) {
      int r = w * 32 + (lane >> 2) + j * 16;
      int cl = (lane & 3) ^ ((r >> 1) & 3);
      GLDS16(A + (size_t)(bm + r) * Kt + k0 + cl * 8, &As[buf][(w * 32 + j * 16) * 32]);
    }
    if (BN == 128) {
#pragma unroll
      for (int j = 0; j < 2; ++j) {
        int r = w * 32 + (lane >> 2) + j * 16;
        int cl = (lane & 3) ^ ((r >> 1) & 3);
        GLDS16(Wt + (size_t)(bn + r) * Kt + k0 + cl * 8, &Bs[buf][(w * 32 + j * 16) * 32]);
      }
    } else {
      int r = w * 16 + (lane >> 2);
      int cl = (lane & 3) ^ ((r >> 1) & 3);
      GLDS16(Wt + (size_t)(bn + r) * Kt + k0 + cl * 8, &Bs[buf][(w * 16) * 32]);
    }
  };

  stage(0, kbeg);
  __syncthreads();
  int cur = 0;

  for (int k0 = kbeg; k0 < kend; k0 += 32) {
    if (k0 + 32 < kend) stage(cur ^ 1, k0 + 32);
    bf16x8 af[4], bfr[NI];
#pragma unroll
    for (int i = 0; i < 4; ++i) {
      int ar = wm + i * 16 + (lane & 15);
      int ac = (lane >> 4) ^ ((ar >> 1) & 3);
      af[i] = *(const bf16x8*)&As[cur][ar * 32 + ac * 8];
    }
#pragma unroll
    for (int i = 0; i < NI; ++i) {
      int br = wn + i * 16 + (lane & 15);
      int bc = (lane >> 4) ^ ((br >> 1) & 3);
      bfr[i] = *(const bf16x8*)&Bs[cur][br * 32 + bc * 8];
    }
#pragma unroll
    for (int mi = 0; mi < 4; ++mi)
#pragma unroll
      for (int ni = 0; ni < NI; ++ni)
        acc[mi][ni] = __builtin_amdgcn_mfma_f32_16x16x32_bf16(af[mi], bfr[ni], acc[mi][ni], 0, 0, 0);
    __syncthreads();
    cur ^= 1;
  }

  const size_t MN = (size_t)gridDim.y * 128 * N;
#pragma unroll
  for (int mi = 0; mi < 4; ++mi) {
#pragma unroll
    for (int ni = 0; ni < NI; ++ni) {
#pragma unroll
      for (int r = 0; r < 4; ++r) {
        int row = bm + wm + mi * 16 + (lane >> 4) * 4 + r;
        int col = bn + wn + ni * 16 + (lane & 15);
        float v = acc[mi][ni][r];
        size_t o = (size_t)row * N + col;
        if (EPI == 3) {
          part[(size_t)sp * MN + o] = v;
        } else {
          if (bias) v += bias[col];
          if (EPI == 1) v = 0.5f * v * (1.0f + erff(v * 0.70710678118f));
          if (EPI == 2) outF[o] = v + resid[o];
          else if (EPI != 2) outB[o] = f2bf(v);
        }
      }
    }
  }
}

// ---------------- split-K combine: out = sum(part) + bias + resid (N = 512 fixed) ----------------
template <int NS>
__global__ __launch_bounds__(256) void comb_k(const float* __restrict__ part,
                                              const float* __restrict__ bias,
                                              const float* __restrict__ resid,
                                              float* __restrict__ outF) {
  size_t idx = ((size_t)blockIdx.x * 256 + threadIdx.x) * 4;  // over ROWS*512
  int col = (int)(idx & 511);
  f32x4 v = *(const f32x4*)&part[idx];
#pragma unroll
  for (int s = 1; s < NS; ++s)
    v += *(const f32x4*)&part[(size_t)s * ROWS * 512 + idx];
  v += *(const f32x4*)&bias[col];
  v += *(const f32x4*)&resid[idx];
  *(f32x4*)&outF[idx] = v;
}

// ---------------- repack qkv -> q,k [bh][n][dh] ----------------
__global__ __launch_bounds__(256) void repack_qk(const unsigned short* __restrict__ qkv,
                                                 unsigned short* __restrict__ q,
                                                 unsigned short* __restrict__ k) {
  int idx = blockIdx.x * 256 + threadIdx.x;  // over BB*SEQL*INNERD = 2^21
  int d = idx & (INNERD - 1);
  int n = (idx >> 9) & (SEQL - 1);
  int b = idx >> 20;
  int h = d >> 6, dh = d & 63;
  size_t src = (size_t)(b * SEQL + n) * 1536 + d;
  size_t dst = ((size_t)(b * NHEADS + h) * SEQL + n) * DHH + dh;
  q[dst] = qkv[src];
  k[dst] = qkv[src + INNERD];
}

// ---------------- v -> vt [bh][dh][n] via LDS transpose ----------------
__global__ __launch_bounds__(256) void transpose_v(const unsigned short* __restrict__ qkv,
                                                   unsigned short* __restrict__ vt) {
  __shared__ unsigned short t[64][65];
  int bh = blockIdx.x;  // 16
  int nt = blockIdx.y;  // 32
  int b = bh >> 3, h = bh & 7;
  for (int i = threadIdx.x; i < 64 * 64; i += 256) {
    int n = i >> 6, dh = i & 63;
    t[n][dh] = qkv[(size_t)(b * SEQL + nt * 64 + n) * 1536 + 2 * INNERD + h * 64 + dh];
  }
  __syncthreads();
  for (int i = threadIdx.x; i < 64 * 64; i += 256) {
    int dh = i >> 6, n = i & 63;
    vt[((size_t)bh * DHH + dh) * SEQL + nt * 64 + n] = t[n][dh];
  }
}

// ---------------- flash attention, KV-split, swapped-QK^T, log2-domain softmax + defer-max ----------------
__global__ __launch_bounds__(256, 4)
void attn_split(const unsigned short* __restrict__ qg,
                const unsigned short* __restrict__ kg,
                const unsigned short* __restrict__ vtg,
                const float* __restrict__ maskadd,
                unsigned short* __restrict__ opart,  // [NSPLIT][16][SEQL][DHH] bf16 (unnormalized)
                float* __restrict__ mlpart) {       // [NSPLIT][16][SEQL][2], m in log2 domain
  __shared__ __align__(16) unsigned short Ks[64 * 64];
  __shared__ __align__(16) unsigned short Vts[64 * 64];
  __shared__ __align__(16) unsigned short Ps[4 * 16 * 64];
  const int tid = threadIdx.x, w = tid >> 6, lane = tid & 63;
  const int g = lane >> 4, c = lane & 15;
  const int bh = blockIdx.y, b = bh >> 3;
  const int qt = blockIdx.x;
  const int split = blockIdx.z;
  const int kv0 = split * KPS;
  const int q0 = qt * 64 + w * 16;
  const float* maskb = maskadd + b * SEQL;

  bf16x8 qf[2];
#pragma unroll
  for (int kb = 0; kb < 2; ++kb)
    qf[kb] = *(const bf16x8*)&qg[((size_t)bh * SEQL + q0 + c) * DHH + kb * 32 + g * 8];
  const float mq = maskb[q0 + c];

  float m_q = NEGF, l_q = 0.f;
  f32x4 o[4] = {};
  unsigned short* myP = &Ps[w * 1024];

  for (int kt = 0; kt < KPS / 64; ++kt) {
#pragma unroll
    for (int j = 0; j < 2; ++j) {
      int r = w * 16 + j * 8 + (lane >> 3);
      int cl = (lane & 7) ^ (r & 7);
      GLDS16(kg + ((size_t)bh * SEQL + kv0 + kt * 64 + r) * DHH + cl * 8, &Ks[(w * 16 + j * 8) * 64]);
      GLDS16(vtg + ((size_t)bh * DHH + r) * SEQL + kv0 + kt * 64 + cl * 8, &Vts[(w * 16 + j * 8) * 64]);
    }
    __syncthreads();

    // S^T = K @ Q^T : lane holds S[k = nt*16+g*4+r][q = c]
    f32x4 sT[4] = {};
#pragma unroll
    for (int nt = 0; nt < 4; ++nt) {
#pragma unroll
      for (int kb = 0; kb < 2; ++kb) {
        int kr = nt * 16 + c;
        int cs = (kb * 4 + g) ^ (kr & 7);
        bf16x8 kf = *(const bf16x8*)&Ks[kr * 64 + cs * 8];
        sT[nt] = __builtin_amdgcn_mfma_f32_16x16x32_bf16(kf, qf[kb], sT[nt], 0, 0, 0);
      }
    }

    // scaled (log2 domain) + additive mask; clamp keeps masked-q rows exactly uniform
    float mx = NEGF;
#pragma unroll
    for (int nt = 0; nt < 4; ++nt) {
      f32x4 mk = *(const f32x4*)&maskb[kv0 + kt * 64 + nt * 16 + g * 4];
#pragma unroll
      for (int r = 0; r < 4; ++r) {
        float x = sT[nt][r] * SCL2 + fmaxf(mq + mk[r], MNEG);
        sT[nt][r] = x;
        mx = fmaxf(mx, x);
      }
    }
    mx = fmaxf(mx, __shfl_xor(mx, 16));
    mx = fmaxf(mx, __shfl_xor(mx, 32));

    // defer-max (THR=8 in log2 units): skip m-update + O-rescale when bounded
    if (!__all(mx <= m_q + 8.f)) {
      float mn = fmaxf(m_q, mx);
      float sf = exp2f(m_q - mn);
      m_q = mn;
      l_q *= sf;
      float sfq[4];
#pragma unroll
      for (int r = 0; r < 4; ++r) sfq[r] = __shfl(sf, g * 4 + r);
#pragma unroll
      for (int ni = 0; ni < 4; ++ni)
#pragma unroll
        for (int r = 0; r < 4; ++r) o[ni][r] *= sfq[r];
    }

    // P = exp2(S - m), pack via v_cvt_pk_bf16_f32, write to wave-private LDS (slot-swizzled)
    float rs = 0.f;
#pragma unroll
    for (int nt = 0; nt < 4; ++nt) {
      float pv0 = exp2f(sT[nt][0] - m_q), pv1 = exp2f(sT[nt][1] - m_q);
      float pv2 = exp2f(sT[nt][2] - m_q), pv3 = exp2f(sT[nt][3] - m_q);
      rs += (pv0 + pv1) + (pv2 + pv3);
      unsigned int lo = cvtpk(pv0, pv1), hi = cvtpk(pv2, pv3);
      int off = c * 64 + (((nt * 2 + (g >> 1)) ^ (c & 7)) << 3) + ((g & 1) << 2);
      *(uint2*)(myP + off) = make_uint2(lo, hi);
    }
    rs += __shfl_xor(rs, 16);
    rs += __shfl_xor(rs, 32);
    l_q += rs;

    // PV: A = P (from wave-private LDS), B = Vt
#pragma unroll
    for (int kb = 0; kb < 2; ++kb) {
      bf16x8 pf = *(const bf16x8*)&myP[c * 64 + (((kb * 4 + g) ^ (c & 7)) << 3)];
#pragma unroll
      for (int ni = 0; ni < 4; ++ni) {
        int vr = ni * 16 + c;
        int vc = (kb * 4 + g) ^ (vr & 7);
        bf16x8 vf = *(const bf16x8*)&Vts[vr * 64 + vc * 8];
        o[ni] = __builtin_amdgcn_mfma_f32_16x16x32_bf16(pf, vf, o[ni], 0, 0, 0);
      }
    }
    __syncthreads();
  }

  const size_t pb = ((size_t)split * 16 + bh) * SEQL;
#pragma unroll
  for (int ni = 0; ni < 4; ++ni)
#pragma unroll
    for (int r = 0; r < 4; ++r)
      opart[(pb + q0 + g * 4 + r) * DHH + ni * 16 + c] = f2bf(o[ni][r]);
  if (lane < 16) {
    size_t mo = (pb + q0 + lane) * 2;
    mlpart[mo] = m_q;
    mlpart[mo + 1] = l_q;
  }
}

__global__ __launch_bounds__(256) void attn_combine(const unsigned short* __restrict__ opart,
                                                    const float* __restrict__ mlpart,
                                                    unsigned short* __restrict__ ctx) {
  int idx = blockIdx.x * 256 + threadIdx.x;  // 16*SEQL*DHH = 2M
  int d = idx & 63, q = (idx >> 6) & (SEQL - 1), bh = idx >> 17;
  float m[NSPLIT], l[NSPLIT], M = NEGF;
#pragma unroll
  for (int s = 0; s < NSPLIT; ++s) {
    size_t mo = (((size_t)s * 16 + bh) * SEQL + q) * 2;
    m[s] = mlpart[mo];
    l[s] = mlpart[mo + 1];
    M = fmaxf(M, m[s]);
  }
  float L = 0.f, ov = 0.f;
#pragma unroll
  for (int s = 0; s < NSPLIT; ++s) {
    float e = exp2f(m[s] - M);  // log2 domain
    L += l[s] * e;
    ov += bf2f(opart[(((size_t)s * 16 + bh) * SEQL + q) * DHH + d]) * e;
  }
  int b = bh >> 3, h = bh & 7;
  ctx[((size_t)(b * SEQL + q)) * INNERD + h * 64 + d] = f2bf(ov / L);
}

// ---------------- host ----------------
extern "C" void kernel_launch(void* const* d_in, const int* in_sizes, int n_in,
                              void* d_out, int out_size, void* d_ws, size_t ws_size,
                              hipStream_t stream) {
  (void)in_sizes; (void)n_in; (void)out_size;
  const float* x_in = (const float*)d_in[0];
  const int* mask = (const int*)d_in[1];
  const float* qkv_w = (const float*)d_in[2];
  const float* out_w = (const float*)d_in[3];
  const float* out_b = (const float*)d_in[4];
  const float* ff_w1 = (const float*)d_in[5];
  const float* ff_b1 = (const float*)d_in[6];
  const float* ff_w2 = (const float*)d_in[7];
  const float* ff_b2 = (const float*)d_in[8];
  const float* ad1w = (const float*)d_in[9];
  const float* ad1b = (const float*)d_in[10];
  const float* ad2w = (const float*)d_in[11];
  const float* ad2b = (const float*)d_in[12];

  char* ws = (char*)d_ws;
  size_t off = 0;
  auto alloc = [&](size_t bytes) {
    char* p = ws + off;
    off = (off + bytes + 255) & ~(size_t)255;
    return p;
  };
  unsigned short* wtQ = (unsigned short*)alloc((size_t)DEPTHL * 1536 * 512 * 2);
  unsigned short* wtO = (unsigned short*)alloc((size_t)DEPTHL * 512 * 512 * 2);
  unsigned short* wtF1 = (unsigned short*)alloc((size_t)DEPTHL * 2048 * 512 * 2);
  unsigned short* wtF2 = (unsigned short*)alloc((size_t)DEPTHL * 512 * 2048 * 2);
  float* xc = (float*)alloc((size_t)ROWS * DIMM * 4);
  unsigned short* hbf = (unsigned short*)alloc((size_t)ROWS * DIMM * 2);
  unsigned short* qkvbf = (unsigned short*)alloc((size_t)ROWS * 1536 * 2);
  char* region2 = alloc((size_t)4 * 16 * SEQL * DHH * 2);  // q,k,vt,ctx OR h1
  unsigned short* qb = (unsigned short*)region2;
  unsigned short* kb = qb + (size_t)16 * SEQL * DHH;
  unsigned short* vtb = kb + (size_t)16 * SEQL * DHH;
  unsigned short* ctxb = vtb + (size_t)16 * SEQL * DHH;
  unsigned short* h1bf = (unsigned short*)region2;  // aliases q/k/vt/ctx (disjoint lifetime)
  float* p1 = (float*)alloc((size_t)BB * 32 * DIMM * 4);
  float* p2 = (float*)alloc((size_t)BB * 32 * DIMM * 4);
  float* alpha = (float*)alloc((size_t)BB * DIMM * 4);
  float* beta = (float*)alloc((size_t)BB * DIMM * 4);
  float* maskadd = (float*)alloc((size_t)BB * SEQL * 4);
  unsigned short* opart = (unsigned short*)alloc((size_t)NSPLIT * 16 * SEQL * DHH * 2);
  float* mlpart = (float*)alloc((size_t)NSPLIT * 16 * SEQL * 2 * 4);
  float* part = (float*)alloc((size_t)4 * ROWS * 512 * 4);  // 32MB split-K partials
  const bool fits = off <= ws_size;  // graceful fallback if workspace too small

  // x working copy
  hipMemcpyAsync(xc, x_in, (size_t)ROWS * DIMM * 4, hipMemcpyDeviceToDevice, stream);

  // weights -> bf16 transposed [N][K]
  wtrans<<<dim3(512 / 32, 1536 / 32, DEPTHL), 256, 0, stream>>>(qkv_w, wtQ, 512, 1536);
  wtrans<<<dim3(512 / 32, 512 / 32, DEPTHL), 256, 0, stream>>>(out_w, wtO, 512, 512);
  wtrans<<<dim3(512 / 32, 2048 / 32, DEPTHL), 256, 0, stream>>>(ff_w1, wtF1, 512, 2048);
  wtrans<<<dim3(2048 / 32, 512 / 32, DEPTHL), 256, 0, stream>>>(ff_w2, wtF2, 2048, 512);
  maskbuild<<<BB * SEQL / 256, 256, 0, stream>>>(mask, maskadd);

  for (int l = 0; l < DEPTHL; ++l) {
    // adain 1
    adain_p1<<<dim3(32, BB), 512, 0, stream>>>(xc, p1, p2);
    adain_p2<<<BB, 512, 0, stream>>>(p1, p2, ad1w + l * BB * DIMM, ad1b + l * BB * DIMM, alpha, beta);
    adain_apply<<<8192, 256, 0, stream>>>(xc, alpha, beta, hbf);
    // qkv: [4096,512] x [512,1536] -> bf16
    gemm_k<0, 64><<<dim3(1536 / 64, ROWS / 128), 256, 0, stream>>>(
        hbf, wtQ + (size_t)l * 1536 * 512, nullptr, nullptr, nullptr, qkvbf, nullptr, 1536, 512);
    repack_qk<<<8192, 256, 0, stream>>>(qkvbf, qb, kb);
    transpose_v<<<dim3(16, 32), 256, 0, stream>>>(qkvbf, vtb);
    attn_split<<<dim3(SEQL / 64, 16, NSPLIT), 256, 0, stream>>>(qb, kb, vtb, maskadd, opart, mlpart);
    attn_combine<<<16 * SEQL * DHH / 256, 256, 0, stream>>>(opart, mlpart, ctxb);
    // out proj + residual (in place on xc)
    if (fits) {
      gemm_k<3, 64><<<dim3(512 / 64, ROWS / 128, 2), 256, 0, stream>>>(
          ctxb, wtO + (size_t)l * 512 * 512, nullptr, nullptr, nullptr, nullptr, part, 512, 512);
      comb_k<2><<<ROWS * 512 / 1024, 256, 0, stream>>>(part, out_b + l * DIMM, xc, xc);
    } else {
      gemm_k<2, 64><<<dim3(512 / 64, ROWS / 128), 256, 0, stream>>>(
          ctxb, wtO + (size_t)l * 512 * 512, out_b + l * DIMM, xc, xc, nullptr, nullptr, 512, 512);
    }
    // adain 2
    adain_p1<<<dim3(32, BB), 512, 0, stream>>>(xc, p1, p2);
    adain_p2<<<BB, 512, 0, stream>>>(p1, p2, ad2w + l * BB * DIMM, ad2b + l * BB * DIMM, alpha, beta);
    adain_apply<<<8192, 256, 0, stream>>>(xc, alpha, beta, hbf);
    // ff1 (gelu) -> h1
    gemm_k<1, 64><<<dim3(2048 / 64, ROWS / 128), 256, 0, stream>>>(
        hbf, wtF1 + (size_t)l * 2048 * 512, ff_b1 + l * MLPD, nullptr, nullptr, h1bf, nullptr, 2048, 512);
    // ff2 + residual
    float* xout = (l == DEPTHL - 1) ? (float*)d_out : xc;
    if (fits) {
      gemm_k<3, 64><<<dim3(512 / 64, ROWS / 128, 4), 256, 0, stream>>>(
          h1bf, wtF2 + (size_t)l * 512 * 2048, nullptr, nullptr, nullptr, nullptr, part, 512, 2048);
      comb_k<4><<<ROWS * 512 / 1024, 256, 0, stream>>>(part, ff_b2 + l * DIMM, xc, xout);
    } else {
      gemm_k<2, 64><<<dim3(512 / 64, ROWS / 128), 256, 0, stream>>>(
          h1bf, wtF2 + (size_t)l * 512 * 2048, ff_b2 + l * DIMM, xc, xout, nullptr, nullptr, 512, 2048);
    }
  }
}

// Round 6
// 337.381 us; speedup vs baseline: 1.6061x; 1.0452x over previous
//
#include <hip/hip_runtime.h>
#include <hip/hip_bf16.h>

#define DEPTHL 2
#define DIMM   512
#define NHEADS 8
#define DHH    64
#define INNERD 512
#define MLPD   2048
#define BB     2
#define SEQL   2048
#define ROWS   (BB*SEQL)
#define MNEG   (-1.0e38f)
#define SCLQ   0.18033688f   /* 0.125 * log2(e), folded into Q */
#define NSPLIT 4
#define KPS    (SEQL / NSPLIT)

typedef __attribute__((ext_vector_type(4))) float f32x4;
typedef __attribute__((ext_vector_type(8))) __bf16 bf16x8;

#define GLDS16(g, l) __builtin_amdgcn_global_load_lds((const __attribute__((address_space(1))) void*)(g), (__attribute__((address_space(3))) void*)(l), 16, 0, 0)

__device__ __forceinline__ unsigned short f2bf(float f) {
  union { float f; unsigned int u; } v; v.f = f;
  unsigned int r = v.u + 0x7fffu + ((v.u >> 16) & 1u);
  return (unsigned short)(r >> 16);
}
__device__ __forceinline__ float bf2f(unsigned short h) {
  union { unsigned int u; float f; } v; v.u = ((unsigned int)h) << 16; return v.f;
}
// packed RNE f32x2 -> bf16x2 (low = a, high = b)
__device__ __forceinline__ unsigned int cvtpk(float a, float b) {
  unsigned int r;
  asm("v_cvt_pk_bf16_f32 %0, %1, %2" : "=v"(r) : "v"(a), "v"(b));
  return r;
}

// ---------------- weight transpose fp32[K][N] -> bf16[N][K] ----------------
__global__ __launch_bounds__(256) void wtrans(const float* __restrict__ wsrc,
                                              unsigned short* __restrict__ wdst,
                                              int K, int N) {
  __shared__ float t[32][33];
  const float* src = wsrc + (size_t)blockIdx.z * K * N;
  unsigned short* dst = wdst + (size_t)blockIdx.z * K * N;
  int k0 = blockIdx.x * 32, n0 = blockIdx.y * 32;
  int tx = threadIdx.x & 31, ty = threadIdx.x >> 5;  // 32x8
#pragma unroll
  for (int j = 0; j < 32; j += 8)
    t[ty + j][tx] = src[(size_t)(k0 + ty + j) * N + n0 + tx];
  __syncthreads();
#pragma unroll
  for (int j = 0; j < 32; j += 8)
    dst[(size_t)(n0 + ty + j) * K + k0 + tx] = f2bf(t[tx][ty + j]);
}

// ---------------- adain ----------------
__global__ __launch_bounds__(512) void adain_p1(const float* __restrict__ x,
                                                float* __restrict__ p1, float* __restrict__ p2) {
  int d = threadIdx.x, c = blockIdx.x, b = blockIdx.y;
  const float* xp = x + ((size_t)b * SEQL + c * 64) * DIMM + d;
  float s = 0.f, s2 = 0.f;
  for (int i = 0; i < 64; ++i) { float v = xp[(size_t)i * DIMM]; s += v; s2 += v * v; }
  p1[(b * 32 + c) * DIMM + d] = s;
  p2[(b * 32 + c) * DIMM + d] = s2;
}

__global__ __launch_bounds__(512) void adain_p2(const float* __restrict__ p1, const float* __restrict__ p2,
                                                const float* __restrict__ w, const float* __restrict__ bi,
                                                float* __restrict__ alpha, float* __restrict__ beta) {
  int d = threadIdx.x, b = blockIdx.x;
  float s = 0.f, s2 = 0.f;
  for (int c = 0; c < 32; ++c) { s += p1[(b * 32 + c) * DIMM + d]; s2 += p2[(b * 32 + c) * DIMM + d]; }
  float mean = s * (1.0f / SEQL);
  float var = s2 * (1.0f / SEQL) - mean * mean;
  float a = w[b * DIMM + d] * rsqrtf(var + 1e-6f);
  alpha[b * DIMM + d] = a;
  beta[b * DIMM + d] = bi[b * DIMM + d] - mean * a;
}

__global__ __launch_bounds__(256) void adain_apply(const float* __restrict__ x,
                                                   const float* __restrict__ alpha, const float* __restrict__ beta,
                                                   unsigned short* __restrict__ hb) {
  int idx = blockIdx.x * 256 + threadIdx.x;  // over ROWS*DIMM = 2^21
  int d = idx & (DIMM - 1);
  int b = idx >> 20;  // SEQL*DIMM = 2^20
  hb[idx] = f2bf(x[idx] * alpha[b * DIMM + d] + beta[b * DIMM + d]);
}

// ---------------- mask -> additive float (0 or -1e38) ----------------
__global__ __launch_bounds__(256) void maskbuild(const int* __restrict__ mask, float* __restrict__ maskadd) {
  int i = blockIdx.x * 256 + threadIdx.x;  // B*N = 4096
  maskadd[i] = mask[i] ? 0.f : MNEG;
}

// ---------------- GEMM: out = A[M,Kt](bf16) @ Wt[N,Kt]^T(bf16) ----------------
// EPI: 0 = bf16 out, 1 = gelu->bf16 out, 2 = fp32 out + bias + resid, 3 = fp32 partial (split-K)
template <int EPI, int BN>
__global__ __launch_bounds__(256)
void gemm_k(const unsigned short* __restrict__ A,
            const unsigned short* __restrict__ Wt,
            const float* __restrict__ bias,
            const float* __restrict__ resid,
            float* __restrict__ outF,
            unsigned short* __restrict__ outB,
            float* __restrict__ part,
            int N, int Kt) {
  constexpr int NI = BN / 32;  // B frags / acc cols per wave
  __shared__ __align__(16) unsigned short As[2][128 * 32];
  __shared__ __align__(16) unsigned short Bs[2][BN * 32];
  const int tid = threadIdx.x;
  const int w = tid >> 6, lane = tid & 63;

  // XCD-aware remap within each z-slice
  unsigned int f = blockIdx.y * gridDim.x + blockIdx.x;
  unsigned int grp = f & 7u, idx = f >> 3;
  unsigned int rpx = gridDim.y >> 3;
  unsigned int by = grp * rpx + idx / gridDim.x;
  unsigned int bx = idx % gridDim.x;

  const int bm = by * 128, bn = bx * BN;
  const int wm = (w >> 1) * 64, wn = (w & 1) * (BN / 2);

  // split-K range
  const int nsplit = gridDim.z, sp = blockIdx.z;
  const int Kc = Kt / nsplit;
  const int kbeg = sp * Kc, kend = kbeg + Kc;

  f32x4 acc[4][NI] = {};

  auto stage = [&](int buf, int k0) {
#pragma unroll
    for (int j = 0; j < 2; ++j) {
      int r = w * 32 + (lane >> 2) + j * 16;
      int cl = (lane & 3) ^ ((r >> 1) & 3);
      GLDS16(A + (size_t)(bm + r) * Kt + k0 + cl * 8, &As[buf][(w * 32 + j * 16) * 32]);
    }
    if (BN == 128) {
#pragma unroll
      for (int j = 0; j < 2; ++j) {
        int r = w * 32 + (lane >> 2) + j * 16;
        int cl = (lane & 3) ^ ((r >> 1) & 3);
        GLDS16(Wt + (size_t)(bn + r) * Kt + k0 + cl * 8, &Bs[buf][(w * 32 + j * 16) * 32]);
      }
    } else {
      int r = w * 16 + (lane >> 2);
      int cl = (lane & 3) ^ ((r >> 1) & 3);
      GLDS16(Wt + (size_t)(bn + r) * Kt + k0 + cl * 8, &Bs[buf][(w * 16) * 32]);
    }
  };

  stage(0, kbeg);
  __syncthreads();
  int cur = 0;

  for (int k0 = kbeg; k0 < kend; k0 += 32) {
    if (k0 + 32 < kend) stage(cur ^ 1, k0 + 32);
    bf16x8 af[4], bfr[NI];
#pragma unroll
    for (int i = 0; i < 4; ++i) {
      int ar = wm + i * 16 + (lane & 15);
      int ac = (lane >> 4) ^ ((ar >> 1) & 3);
      af[i] = *(const bf16x8*)&As[cur][ar * 32 + ac * 8];
    }
#pragma unroll
    for (int i = 0; i < NI; ++i) {
      int br = wn + i * 16 + (lane & 15);
      int bc = (lane >> 4) ^ ((br >> 1) & 3);
      bfr[i] = *(const bf16x8*)&Bs[cur][br * 32 + bc * 8];
    }
#pragma unroll
    for (int mi = 0; mi < 4; ++mi)
#pragma unroll
      for (int ni = 0; ni < NI; ++ni)
        acc[mi][ni] = __builtin_amdgcn_mfma_f32_16x16x32_bf16(af[mi], bfr[ni], acc[mi][ni], 0, 0, 0);
    __syncthreads();
    cur ^= 1;
  }

  const size_t MN = (size_t)gridDim.y * 128 * N;
#pragma unroll
  for (int mi = 0; mi < 4; ++mi) {
#pragma unroll
    for (int ni = 0; ni < NI; ++ni) {
#pragma unroll
      for (int r = 0; r < 4; ++r) {
        int row = bm + wm + mi * 16 + (lane >> 4) * 4 + r;
        int col = bn + wn + ni * 16 + (lane & 15);
        float v = acc[mi][ni][r];
        size_t o = (size_t)row * N + col;
        if (EPI == 3) {
          part[(size_t)sp * MN + o] = v;
        } else {
          if (bias) v += bias[col];
          if (EPI == 1) v = 0.5f * v * (1.0f + erff(v * 0.70710678118f));
          if (EPI == 2) outF[o] = v + resid[o];
          else if (EPI != 2) outB[o] = f2bf(v);
        }
      }
    }
  }
}

// ---------------- split-K combine: out = sum(part) + bias + resid (N = 512 fixed) ----------------
template <int NS>
__global__ __launch_bounds__(256) void comb_k(const float* __restrict__ part,
                                              const float* __restrict__ bias,
                                              const float* __restrict__ resid,
                                              float* __restrict__ outF) {
  size_t idx = ((size_t)blockIdx.x * 256 + threadIdx.x) * 4;  // over ROWS*512
  int col = (int)(idx & 511);
  f32x4 v = *(const f32x4*)&part[idx];
#pragma unroll
  for (int s = 1; s < NS; ++s)
    v += *(const f32x4*)&part[(size_t)s * ROWS * 512 + idx];
  v += *(const f32x4*)&bias[col];
  v += *(const f32x4*)&resid[idx];
  *(f32x4*)&outF[idx] = v;
}

// ---------------- repack qkv -> q (pre-scaled by 0.125*log2e), k [bh][n][dh] ----------------
__global__ __launch_bounds__(256) void repack_qk(const unsigned short* __restrict__ qkv,
                                                 unsigned short* __restrict__ q,
                                                 unsigned short* __restrict__ k) {
  int idx = blockIdx.x * 256 + threadIdx.x;  // over BB*SEQL*INNERD = 2^21
  int d = idx & (INNERD - 1);
  int n = (idx >> 9) & (SEQL - 1);
  int b = idx >> 20;
  int h = d >> 6, dh = d & 63;
  size_t src = (size_t)(b * SEQL + n) * 1536 + d;
  size_t dst = ((size_t)(b * NHEADS + h) * SEQL + n) * DHH + dh;
  q[dst] = f2bf(bf2f(qkv[src]) * SCLQ);
  k[dst] = qkv[src + INNERD];
}

// ---------------- v -> vt [bh][dh][n] via LDS transpose ----------------
__global__ __launch_bounds__(256) void transpose_v(const unsigned short* __restrict__ qkv,
                                                   unsigned short* __restrict__ vt) {
  __shared__ unsigned short t[64][65];
  int bh = blockIdx.x;  // 16
  int nt = blockIdx.y;  // 32
  int b = bh >> 3, h = bh & 7;
  for (int i = threadIdx.x; i < 64 * 64; i += 256) {
    int n = i >> 6, dh = i & 63;
    t[n][dh] = qkv[(size_t)(b * SEQL + nt * 64 + n) * 1536 + 2 * INNERD + h * 64 + dh];
  }
  __syncthreads();
  for (int i = threadIdx.x; i < 64 * 64; i += 256) {
    int dh = i >> 6, n = i & 63;
    vt[((size_t)bh * DHH + dh) * SEQL + nt * 64 + n] = t[n][dh];
  }
}

// ---------------- V column means (for masked-q uniform-attention rows) ----------------
__global__ __launch_bounds__(256) void vmean_k(const unsigned short* __restrict__ vt,
                                               float* __restrict__ vmean) {
  // grid (16 bh, 8 d-octets); thread: d = y*8 + (t>>5), seg = t&31 covers 64 n
  __shared__ float red[256];
  int bh = blockIdx.x, t = threadIdx.x;
  int d = blockIdx.y * 8 + (t >> 5), seg = t & 31;
  const unsigned short* p = vt + ((size_t)bh * 64 + d) * SEQL + seg * 64;
  float s = 0.f;
#pragma unroll
  for (int i = 0; i < 16; ++i) {
    uint2 v = *(const uint2*)&p[i * 4];
    s += bf2f(v.x & 0xffff) + bf2f(v.x >> 16) + bf2f(v.y & 0xffff) + bf2f(v.y >> 16);
  }
  red[t] = s;
  __syncthreads();
  if (t < 8) {
    float a = 0.f;
#pragma unroll
    for (int i = 0; i < 32; ++i) a += red[t * 32 + i];
    vmean[bh * 64 + blockIdx.y * 8 + t] = a * (1.0f / SEQL);
  }
}

// ---------------- flash attention, KV-split, swapped-QK^T, fixed-zero-max softmax ----------------
__global__ __launch_bounds__(256, 4)
void attn_split(const unsigned short* __restrict__ qg,
                const unsigned short* __restrict__ kg,
                const unsigned short* __restrict__ vtg,
                const float* __restrict__ maskadd,
                unsigned short* __restrict__ opart,  // [NSPLIT][16][SEQL][DHH] bf16 (unnormalized)
                float* __restrict__ lpart) {        // [NSPLIT][16][SEQL]
  __shared__ __align__(16) unsigned short Ks[64 * 64];
  __shared__ __align__(16) unsigned short Vts[64 * 64];
  __shared__ __align__(16) unsigned short Ps[4 * 16 * 64];
  const int tid = threadIdx.x, w = tid >> 6, lane = tid & 63;
  const int g = lane >> 4, c = lane & 15;
  const int bh = blockIdx.y, b = bh >> 3;
  const int qt = blockIdx.x;
  const int split = blockIdx.z;
  const int kv0 = split * KPS;
  const int q0 = qt * 64 + w * 16;
  const float* maskb = maskadd + b * SEQL;

  bf16x8 qf[2];
#pragma unroll
  for (int kb = 0; kb < 2; ++kb)
    qf[kb] = *(const bf16x8*)&qg[((size_t)bh * SEQL + q0 + c) * DHH + kb * 32 + g * 8];

  float l_acc = 0.f;
  f32x4 o[4] = {};
  unsigned short* myP = &Ps[w * 1024];

  for (int kt = 0; kt < KPS / 64; ++kt) {
#pragma unroll
    for (int j = 0; j < 2; ++j) {
      int r = w * 16 + j * 8 + (lane >> 3);
      int cl = (lane & 7) ^ (r & 7);
      GLDS16(kg + ((size_t)bh * SEQL + kv0 + kt * 64 + r) * DHH + cl * 8, &Ks[(w * 16 + j * 8) * 64]);
      GLDS16(vtg + ((size_t)bh * DHH + r) * SEQL + kv0 + kt * 64 + cl * 8, &Vts[(w * 16 + j * 8) * 64]);
    }
    __syncthreads();

    // S^T = K @ Q^T : lane holds S[k = nt*16+g*4+r][q = c], already in log2 domain (Q pre-scaled)
    f32x4 sT[4] = {};
#pragma unroll
    for (int nt = 0; nt < 4; ++nt) {
#pragma unroll
      for (int kb = 0; kb < 2; ++kb) {
        int kr = nt * 16 + c;
        int cs = (kb * 4 + g) ^ (kr & 7);
        bf16x8 kf = *(const bf16x8*)&Ks[kr * 64 + cs * 8];
        sT[nt] = __builtin_amdgcn_mfma_f32_16x16x32_bf16(kf, qf[kb], sT[nt], 0, 0, 0);
      }
    }

    // p = exp2(S + mask), fixed m = 0 (scores bounded; shift-invariant softmax)
#pragma unroll
    for (int nt = 0; nt < 4; ++nt) {
      f32x4 mk = *(const f32x4*)&maskb[kv0 + kt * 64 + nt * 16 + g * 4];
      float pv0 = exp2f(sT[nt][0] + mk[0]), pv1 = exp2f(sT[nt][1] + mk[1]);
      float pv2 = exp2f(sT[nt][2] + mk[2]), pv3 = exp2f(sT[nt][3] + mk[3]);
      l_acc += (pv0 + pv1) + (pv2 + pv3);
      unsigned int lo = cvtpk(pv0, pv1), hi = cvtpk(pv2, pv3);
      int off = c * 64 + (((nt * 2 + (g >> 1)) ^ (c & 7)) << 3) + ((g & 1) << 2);
      *(uint2*)(myP + off) = make_uint2(lo, hi);
    }

    // PV: A = P (from wave-private LDS), B = Vt
#pragma unroll
    for (int kb = 0; kb < 2; ++kb) {
      bf16x8 pf = *(const bf16x8*)&myP[c * 64 + (((kb * 4 + g) ^ (c & 7)) << 3)];
#pragma unroll
      for (int ni = 0; ni < 4; ++ni) {
        int vr = ni * 16 + c;
        int vc = (kb * 4 + g) ^ (vr & 7);
        bf16x8 vf = *(const bf16x8*)&Vts[vr * 64 + vc * 8];
        o[ni] = __builtin_amdgcn_mfma_f32_16x16x32_bf16(pf, vf, o[ni], 0, 0, 0);
      }
    }
    __syncthreads();
  }

  // one reduction at the end: sum l over the 4 k-groups holding q = c
  l_acc += __shfl_xor(l_acc, 16);
  l_acc += __shfl_xor(l_acc, 32);

  const size_t pb = ((size_t)split * 16 + bh) * SEQL;
#pragma unroll
  for (int ni = 0; ni < 4; ++ni)
#pragma unroll
    for (int r = 0; r < 4; ++r)
      opart[(pb + q0 + g * 4 + r) * DHH + ni * 16 + c] = f2bf(o[ni][r]);
  if (lane < 16) lpart[pb + q0 + lane] = l_acc;
}

__global__ __launch_bounds__(256) void attn_combine(const unsigned short* __restrict__ opart,
                                                    const float* __restrict__ lpart,
                                                    const float* __restrict__ maskadd,
                                                    const float* __restrict__ vmean,
                                                    unsigned short* __restrict__ ctx) {
  int idx = blockIdx.x * 256 + threadIdx.x;  // 16*SEQL*16 threads, 4 d each
  int dq = idx & 15;
  int q = (idx >> 4) & (SEQL - 1);
  int bh = idx >> 15;
  int d0 = dq * 4;
  int b = bh >> 3, h = bh & 7;
  float o0 = 0.f, o1 = 0.f, o2 = 0.f, o3 = 0.f, L = 0.f;
#pragma unroll
  for (int s = 0; s < NSPLIT; ++s) {
    size_t base = ((size_t)s * 16 + bh) * SEQL + q;
    L += lpart[base];
    uint2 v = *(const uint2*)&opart[base * DHH + d0];
    o0 += bf2f(v.x & 0xffff); o1 += bf2f(v.x >> 16);
    o2 += bf2f(v.y & 0xffff); o3 += bf2f(v.y >> 16);
  }
  float r = 1.0f / L;
  o0 *= r; o1 *= r; o2 *= r; o3 *= r;
  if (maskadd[b * SEQL + q] != 0.f) {  // masked q: reference gives uniform attention = mean(V)
    f32x4 vm = *(const f32x4*)&vmean[bh * 64 + d0];
    o0 = vm[0]; o1 = vm[1]; o2 = vm[2]; o3 = vm[3];
  }
  *(uint2*)&ctx[((size_t)(b * SEQL + q)) * INNERD + h * 64 + d0] =
      make_uint2(cvtpk(o0, o1), cvtpk(o2, o3));
}

// ---------------- host ----------------
extern "C" void kernel_launch(void* const* d_in, const int* in_sizes, int n_in,
                              void* d_out, int out_size, void* d_ws, size_t ws_size,
                              hipStream_t stream) {
  (void)in_sizes; (void)n_in; (void)out_size;
  const float* x_in = (const float*)d_in[0];
  const int* mask = (const int*)d_in[1];
  const float* qkv_w = (const float*)d_in[2];
  const float* out_w = (const float*)d_in[3];
  const float* out_b = (const float*)d_in[4];
  const float* ff_w1 = (const float*)d_in[5];
  const float* ff_b1 = (const float*)d_in[6];
  const float* ff_w2 = (const float*)d_in[7];
  const float* ff_b2 = (const float*)d_in[8];
  const float* ad1w = (const float*)d_in[9];
  const float* ad1b = (const float*)d_in[10];
  const float* ad2w = (const float*)d_in[11];
  const float* ad2b = (const float*)d_in[12];

  char* ws = (char*)d_ws;
  size_t off = 0;
  auto alloc = [&](size_t bytes) {
    char* p = ws + off;
    off = (off + bytes + 255) & ~(size_t)255;
    return p;
  };
  unsigned short* wtQ = (unsigned short*)alloc((size_t)DEPTHL * 1536 * 512 * 2);
  unsigned short* wtO = (unsigned short*)alloc((size_t)DEPTHL * 512 * 512 * 2);
  unsigned short* wtF1 = (unsigned short*)alloc((size_t)DEPTHL * 2048 * 512 * 2);
  unsigned short* wtF2 = (unsigned short*)alloc((size_t)DEPTHL * 512 * 2048 * 2);
  float* xc = (float*)alloc((size_t)ROWS * DIMM * 4);
  unsigned short* hbf = (unsigned short*)alloc((size_t)ROWS * DIMM * 2);
  unsigned short* qkvbf = (unsigned short*)alloc((size_t)ROWS * 1536 * 2);
  char* region2 = alloc((size_t)4 * 16 * SEQL * DHH * 2);  // q,k,vt,ctx OR h1
  unsigned short* qb = (unsigned short*)region2;
  unsigned short* kb = qb + (size_t)16 * SEQL * DHH;
  unsigned short* vtb = kb + (size_t)16 * SEQL * DHH;
  unsigned short* ctxb = vtb + (size_t)16 * SEQL * DHH;
  unsigned short* h1bf = (unsigned short*)region2;  // aliases q/k/vt/ctx (disjoint lifetime)
  float* p1 = (float*)alloc((size_t)BB * 32 * DIMM * 4);
  float* p2 = (float*)alloc((size_t)BB * 32 * DIMM * 4);
  float* alpha = (float*)alloc((size_t)BB * DIMM * 4);
  float* beta = (float*)alloc((size_t)BB * DIMM * 4);
  float* maskadd = (float*)alloc((size_t)BB * SEQL * 4);
  unsigned short* opart = (unsigned short*)alloc((size_t)NSPLIT * 16 * SEQL * DHH * 2);
  float* lpart = (float*)alloc((size_t)NSPLIT * 16 * SEQL * 4);
  float* vmean = (float*)alloc((size_t)16 * 64 * 4);
  float* part = (float*)alloc((size_t)4 * ROWS * 512 * 4);  // 32MB split-K partials
  const bool fits = off <= ws_size;  // graceful fallback if workspace too small

  // x working copy
  hipMemcpyAsync(xc, x_in, (size_t)ROWS * DIMM * 4, hipMemcpyDeviceToDevice, stream);

  // weights -> bf16 transposed [N][K]
  wtrans<<<dim3(512 / 32, 1536 / 32, DEPTHL), 256, 0, stream>>>(qkv_w, wtQ, 512, 1536);
  wtrans<<<dim3(512 / 32, 512 / 32, DEPTHL), 256, 0, stream>>>(out_w, wtO, 512, 512);
  wtrans<<<dim3(512 / 32, 2048 / 32, DEPTHL), 256, 0, stream>>>(ff_w1, wtF1, 512, 2048);
  wtrans<<<dim3(2048 / 32, 512 / 32, DEPTHL), 256, 0, stream>>>(ff_w2, wtF2, 2048, 512);
  maskbuild<<<BB * SEQL / 256, 256, 0, stream>>>(mask, maskadd);

  for (int l = 0; l < DEPTHL; ++l) {
    // adain 1
    adain_p1<<<dim3(32, BB), 512, 0, stream>>>(xc, p1, p2);
    adain_p2<<<BB, 512, 0, stream>>>(p1, p2, ad1w + l * BB * DIMM, ad1b + l * BB * DIMM, alpha, beta);
    adain_apply<<<8192, 256, 0, stream>>>(xc, alpha, beta, hbf);
    // qkv: [4096,512] x [512,1536] -> bf16
    gemm_k<0, 64><<<dim3(1536 / 64, ROWS / 128), 256, 0, stream>>>(
        hbf, wtQ + (size_t)l * 1536 * 512, nullptr, nullptr, nullptr, qkvbf, nullptr, 1536, 512);
    repack_qk<<<8192, 256, 0, stream>>>(qkvbf, qb, kb);
    transpose_v<<<dim3(16, 32), 256, 0, stream>>>(qkvbf, vtb);
    vmean_k<<<dim3(16, 8), 256, 0, stream>>>(vtb, vmean);
    attn_split<<<dim3(SEQL / 64, 16, NSPLIT), 256, 0, stream>>>(qb, kb, vtb, maskadd, opart, lpart);
    attn_combine<<<16 * SEQL * 16 / 256, 256, 0, stream>>>(opart, lpart, maskadd, vmean, ctxb);
    // out proj + residual (in place on xc)
    if (fits) {
      gemm_k<3, 64><<<dim3(512 / 64, ROWS / 128, 2), 256, 0, stream>>>(
          ctxb, wtO + (size_t)l * 512 * 512, nullptr, nullptr, nullptr, nullptr, part, 512, 512);
      comb_k<2><<<ROWS * 512 / 1024, 256, 0, stream>>>(part, out_b + l * DIMM, xc, xc);
    } else {
      gemm_k<2, 64><<<dim3(512 / 64, ROWS / 128), 256, 0, stream>>>(
          ctxb, wtO + (size_t)l * 512 * 512, out_b + l * DIMM, xc, xc, nullptr, nullptr, 512, 512);
    }
    // adain 2
    adain_p1<<<dim3(32, BB), 512, 0, stream>>>(xc, p1, p2);
    adain_p2<<<BB, 512, 0, stream>>>(p1, p2, ad2w + l * BB * DIMM, ad2b + l * BB * DIMM, alpha, beta);
    adain_apply<<<8192, 256, 0, stream>>>(xc, alpha, beta, hbf);
    // ff1 (gelu) -> h1
    gemm_k<1, 64><<<dim3(2048 / 64, ROWS / 128), 256, 0, stream>>>(
        hbf, wtF1 + (size_t)l * 2048 * 512, ff_b1 + l * MLPD, nullptr, nullptr, h1bf, nullptr, 2048, 512);
    // ff2 + residual
    float* xout = (l == DEPTHL - 1) ? (float*)d_out : xc;
    if (fits) {
      gemm_k<3, 64><<<dim3(512 / 64, ROWS / 128, 4), 256, 0, stream>>>(
          h1bf, wtF2 + (size_t)l * 512 * 2048, nullptr, nullptr, nullptr, nullptr, part, 512, 2048);
      comb_k<4><<<ROWS * 512 / 1024, 256, 0, stream>>>(part, ff_b2 + l * DIMM, xc, xout);
    } else {
      gemm_k<2, 64><<<dim3(512 / 64, ROWS / 128), 256, 0, stream>>>(
          h1bf, wtF2 + (size_t)l * 512 * 2048, ff_b2 + l * DIMM, xc, xout, nullptr, nullptr, 512, 2048);
    }
  }
}

// Round 7
// 328.982 us; speedup vs baseline: 1.6471x; 1.0255x over previous
//
#include <hip/hip_runtime.h>
#include <hip/hip_bf16.h>

#define DEPTHL 2
#define DIMM   512
#define NHEADS 8
#define DHH    64
#define INNERD 512
#define MLPD   2048
#define BB     2
#define SEQL   2048
#define ROWS   (BB*SEQL)
#define MNEG   (-1.0e38f)
#define SCLQ   0.18033688f   /* 0.125 * log2(e), folded into Q */
#define NSPLIT 4
#define KPS    (SEQL / NSPLIT)

typedef __attribute__((ext_vector_type(4))) float f32x4;
typedef __attribute__((ext_vector_type(8))) __bf16 bf16x8;

#define GLDS16(g, l) __builtin_amdgcn_global_load_lds((const __attribute__((address_space(1))) void*)(g), (__attribute__((address_space(3))) void*)(l), 16, 0, 0)

__device__ __forceinline__ unsigned short f2bf(float f) {
  union { float f; unsigned int u; } v; v.f = f;
  unsigned int r = v.u + 0x7fffu + ((v.u >> 16) & 1u);
  return (unsigned short)(r >> 16);
}
__device__ __forceinline__ float bf2f(unsigned short h) {
  union { unsigned int u; float f; } v; v.u = ((unsigned int)h) << 16; return v.f;
}
// packed RNE f32x2 -> bf16x2 (low = a, high = b)
__device__ __forceinline__ unsigned int cvtpk(float a, float b) {
  unsigned int r;
  asm("v_cvt_pk_bf16_f32 %0, %1, %2" : "=v"(r) : "v"(a), "v"(b));
  return r;
}

// ---------------- weight transpose fp32[K][N] -> bf16[N][K] ----------------
__global__ __launch_bounds__(256) void wtrans(const float* __restrict__ wsrc,
                                              unsigned short* __restrict__ wdst,
                                              int K, int N) {
  __shared__ float t[32][33];
  const float* src = wsrc + (size_t)blockIdx.z * K * N;
  unsigned short* dst = wdst + (size_t)blockIdx.z * K * N;
  int k0 = blockIdx.x * 32, n0 = blockIdx.y * 32;
  int tx = threadIdx.x & 31, ty = threadIdx.x >> 5;  // 32x8
#pragma unroll
  for (int j = 0; j < 32; j += 8)
    t[ty + j][tx] = src[(size_t)(k0 + ty + j) * N + n0 + tx];
  __syncthreads();
#pragma unroll
  for (int j = 0; j < 32; j += 8)
    dst[(size_t)(n0 + ty + j) * K + k0 + tx] = f2bf(t[tx][ty + j]);
}

// ---------------- adain ----------------
__global__ __launch_bounds__(512) void adain_p1(const float* __restrict__ x,
                                                float* __restrict__ p1, float* __restrict__ p2) {
  int d = threadIdx.x, c = blockIdx.x, b = blockIdx.y;
  const float* xp = x + ((size_t)b * SEQL + c * 64) * DIMM + d;
  float s = 0.f, s2 = 0.f;
  for (int i = 0; i < 64; ++i) { float v = xp[(size_t)i * DIMM]; s += v; s2 += v * v; }
  p1[(b * 32 + c) * DIMM + d] = s;
  p2[(b * 32 + c) * DIMM + d] = s2;
}

__global__ __launch_bounds__(512) void adain_p2(const float* __restrict__ p1, const float* __restrict__ p2,
                                                const float* __restrict__ w, const float* __restrict__ bi,
                                                float* __restrict__ alpha, float* __restrict__ beta) {
  int d = threadIdx.x, b = blockIdx.x;
  float s = 0.f, s2 = 0.f;
  for (int c = 0; c < 32; ++c) { s += p1[(b * 32 + c) * DIMM + d]; s2 += p2[(b * 32 + c) * DIMM + d]; }
  float mean = s * (1.0f / SEQL);
  float var = s2 * (1.0f / SEQL) - mean * mean;
  float a = w[b * DIMM + d] * rsqrtf(var + 1e-6f);
  alpha[b * DIMM + d] = a;
  beta[b * DIMM + d] = bi[b * DIMM + d] - mean * a;
}

__global__ __launch_bounds__(256) void adain_apply(const float* __restrict__ x,
                                                   const float* __restrict__ alpha, const float* __restrict__ beta,
                                                   unsigned short* __restrict__ hb) {
  int idx = blockIdx.x * 256 + threadIdx.x;  // over ROWS*DIMM = 2^21
  int d = idx & (DIMM - 1);
  int b = idx >> 20;  // SEQL*DIMM = 2^20
  hb[idx] = f2bf(x[idx] * alpha[b * DIMM + d] + beta[b * DIMM + d]);
}

// ---------------- mask -> additive float (0 or -1e38) ----------------
__global__ __launch_bounds__(256) void maskbuild(const int* __restrict__ mask, float* __restrict__ maskadd) {
  int i = blockIdx.x * 256 + threadIdx.x;  // B*N = 4096
  maskadd[i] = mask[i] ? 0.f : MNEG;
}

// ---------------- GEMM: out = A[M,Kt](bf16) @ Wt[N,Kt]^T(bf16) ----------------
// EPI: 0 = bf16 out, 1 = gelu->bf16 out, 2 = fp32 out + bias + resid, 3 = bf16 partial (split-K)
template <int EPI, int BN>
__global__ __launch_bounds__(256)
void gemm_k(const unsigned short* __restrict__ A,
            const unsigned short* __restrict__ Wt,
            const float* __restrict__ bias,
            const float* __restrict__ resid,
            float* __restrict__ outF,
            unsigned short* __restrict__ outB,
            unsigned short* __restrict__ part,
            int N, int Kt) {
  constexpr int NI = BN / 32;  // B frags / acc cols per wave
  __shared__ __align__(16) unsigned short As[2][128 * 32];
  __shared__ __align__(16) unsigned short Bs[2][BN * 32];
  const int tid = threadIdx.x;
  const int w = tid >> 6, lane = tid & 63;

  // XCD-aware remap within each z-slice
  unsigned int f = blockIdx.y * gridDim.x + blockIdx.x;
  unsigned int grp = f & 7u, idx = f >> 3;
  unsigned int rpx = gridDim.y >> 3;
  unsigned int by = grp * rpx + idx / gridDim.x;
  unsigned int bx = idx % gridDim.x;

  const int bm = by * 128, bn = bx * BN;
  const int wm = (w >> 1) * 64, wn = (w & 1) * (BN / 2);

  // split-K range
  const int nsplit = gridDim.z, sp = blockIdx.z;
  const int Kc = Kt / nsplit;
  const int kbeg = sp * Kc, kend = kbeg + Kc;

  f32x4 acc[4][NI] = {};

  auto stage = [&](int buf, int k0) {
#pragma unroll
    for (int j = 0; j < 2; ++j) {
      int r = w * 32 + (lane >> 2) + j * 16;
      int cl = (lane & 3) ^ ((r >> 1) & 3);
      GLDS16(A + (size_t)(bm + r) * Kt + k0 + cl * 8, &As[buf][(w * 32 + j * 16) * 32]);
    }
    if (BN == 128) {
#pragma unroll
      for (int j = 0; j < 2; ++j) {
        int r = w * 32 + (lane >> 2) + j * 16;
        int cl = (lane & 3) ^ ((r >> 1) & 3);
        GLDS16(Wt + (size_t)(bn + r) * Kt + k0 + cl * 8, &Bs[buf][(w * 32 + j * 16) * 32]);
      }
    } else {
      int r = w * 16 + (lane >> 2);
      int cl = (lane & 3) ^ ((r >> 1) & 3);
      GLDS16(Wt + (size_t)(bn + r) * Kt + k0 + cl * 8, &Bs[buf][(w * 16) * 32]);
    }
  };

  stage(0, kbeg);
  __syncthreads();
  int cur = 0;

  for (int k0 = kbeg; k0 < kend; k0 += 32) {
    if (k0 + 32 < kend) stage(cur ^ 1, k0 + 32);
    bf16x8 af[4], bfr[NI];
#pragma unroll
    for (int i = 0; i < 4; ++i) {
      int ar = wm + i * 16 + (lane & 15);
      int ac = (lane >> 4) ^ ((ar >> 1) & 3);
      af[i] = *(const bf16x8*)&As[cur][ar * 32 + ac * 8];
    }
#pragma unroll
    for (int i = 0; i < NI; ++i) {
      int br = wn + i * 16 + (lane & 15);
      int bc = (lane >> 4) ^ ((br >> 1) & 3);
      bfr[i] = *(const bf16x8*)&Bs[cur][br * 32 + bc * 8];
    }
#pragma unroll
    for (int mi = 0; mi < 4; ++mi)
#pragma unroll
      for (int ni = 0; ni < NI; ++ni)
        acc[mi][ni] = __builtin_amdgcn_mfma_f32_16x16x32_bf16(af[mi], bfr[ni], acc[mi][ni], 0, 0, 0);
    __syncthreads();
    cur ^= 1;
  }

  const size_t MN = (size_t)gridDim.y * 128 * N;
#pragma unroll
  for (int mi = 0; mi < 4; ++mi) {
#pragma unroll
    for (int ni = 0; ni < NI; ++ni) {
#pragma unroll
      for (int r = 0; r < 4; ++r) {
        int row = bm + wm + mi * 16 + (lane >> 4) * 4 + r;
        int col = bn + wn + ni * 16 + (lane & 15);
        float v = acc[mi][ni][r];
        size_t o = (size_t)row * N + col;
        if (EPI == 3) {
          part[(size_t)sp * MN + o] = f2bf(v);
        } else {
          if (bias) v += bias[col];
          if (EPI == 1) v = 0.5f * v * (1.0f + erff(v * 0.70710678118f));
          if (EPI == 2) outF[o] = v + resid[o];
          else if (EPI != 2) outB[o] = f2bf(v);
        }
      }
    }
  }
}

// ---------------- split-K combine (bf16 partials): out = sum(part) + bias + resid ----------------
template <int NS>
__global__ __launch_bounds__(256) void comb_k(const unsigned short* __restrict__ part,
                                              const float* __restrict__ bias,
                                              const float* __restrict__ resid,
                                              float* __restrict__ outF) {
  size_t idx = ((size_t)blockIdx.x * 256 + threadIdx.x) * 4;  // over ROWS*512
  int col = (int)(idx & 511);
  float a0 = 0.f, a1 = 0.f, a2 = 0.f, a3 = 0.f;
#pragma unroll
  for (int s = 0; s < NS; ++s) {
    uint2 v = *(const uint2*)&part[(size_t)s * ROWS * 512 + idx];
    a0 += bf2f(v.x & 0xffff); a1 += bf2f(v.x >> 16);
    a2 += bf2f(v.y & 0xffff); a3 += bf2f(v.y >> 16);
  }
  f32x4 b = *(const f32x4*)&bias[col];
  f32x4 rs = *(const f32x4*)&resid[idx];
  f32x4 o;
  o[0] = a0 + b[0] + rs[0]; o[1] = a1 + b[1] + rs[1];
  o[2] = a2 + b[2] + rs[2]; o[3] = a3 + b[3] + rs[3];
  *(f32x4*)&outF[idx] = o;
}

// ---------------- repack qkv -> q (pre-scaled by 0.125*log2e), k [bh][n][dh] ----------------
__global__ __launch_bounds__(256) void repack_qk(const unsigned short* __restrict__ qkv,
                                                 unsigned short* __restrict__ q,
                                                 unsigned short* __restrict__ k) {
  int idx = blockIdx.x * 256 + threadIdx.x;  // over BB*SEQL*INNERD = 2^21
  int d = idx & (INNERD - 1);
  int n = (idx >> 9) & (SEQL - 1);
  int b = idx >> 20;
  int h = d >> 6, dh = d & 63;
  size_t src = (size_t)(b * SEQL + n) * 1536 + d;
  size_t dst = ((size_t)(b * NHEADS + h) * SEQL + n) * DHH + dh;
  q[dst] = f2bf(bf2f(qkv[src]) * SCLQ);
  k[dst] = qkv[src + INNERD];
}

// ---------------- v -> vt [bh][dh][n] via LDS transpose ----------------
__global__ __launch_bounds__(256) void transpose_v(const unsigned short* __restrict__ qkv,
                                                   unsigned short* __restrict__ vt) {
  __shared__ unsigned short t[64][65];
  int bh = blockIdx.x;  // 16
  int nt = blockIdx.y;  // 32
  int b = bh >> 3, h = bh & 7;
  for (int i = threadIdx.x; i < 64 * 64; i += 256) {
    int n = i >> 6, dh = i & 63;
    t[n][dh] = qkv[(size_t)(b * SEQL + nt * 64 + n) * 1536 + 2 * INNERD + h * 64 + dh];
  }
  __syncthreads();
  for (int i = threadIdx.x; i < 64 * 64; i += 256) {
    int dh = i >> 6, n = i & 63;
    vt[((size_t)bh * DHH + dh) * SEQL + nt * 64 + n] = t[n][dh];
  }
}

// ---------------- V column means (for masked-q uniform-attention rows) ----------------
__global__ __launch_bounds__(256) void vmean_k(const unsigned short* __restrict__ vt,
                                               float* __restrict__ vmean) {
  __shared__ float red[256];
  int bh = blockIdx.x, t = threadIdx.x;
  int d = blockIdx.y * 8 + (t >> 5), seg = t & 31;
  const unsigned short* p = vt + ((size_t)bh * 64 + d) * SEQL + seg * 64;
  float s = 0.f;
#pragma unroll
  for (int i = 0; i < 16; ++i) {
    uint2 v = *(const uint2*)&p[i * 4];
    s += bf2f(v.x & 0xffff) + bf2f(v.x >> 16) + bf2f(v.y & 0xffff) + bf2f(v.y >> 16);
  }
  red[t] = s;
  __syncthreads();
  if (t < 8) {
    float a = 0.f;
#pragma unroll
    for (int i = 0; i < 32; ++i) a += red[t * 32 + i];
    vmean[bh * 64 + blockIdx.y * 8 + t] = a * (1.0f / SEQL);
  }
}

// ---------------- flash attention: mask via MFMA C-init, l via ones-MFMA ----------------
__global__ __launch_bounds__(256, 4)
void attn_split(const unsigned short* __restrict__ qg,
                const unsigned short* __restrict__ kg,
                const unsigned short* __restrict__ vtg,
                const float* __restrict__ maskadd,
                unsigned short* __restrict__ opart,  // [NSPLIT][16][SEQL][DHH] bf16 (unnormalized)
                float* __restrict__ lpart) {        // [NSPLIT][16][SEQL]
  __shared__ __align__(16) unsigned short Ks[64 * 64];
  __shared__ __align__(16) unsigned short Vts[64 * 64];
  __shared__ __align__(16) unsigned short Ps[4 * 16 * 64];
  const int tid = threadIdx.x, w = tid >> 6, lane = tid & 63;
  const int g = lane >> 4, c = lane & 15;
  const int bh = blockIdx.y, b = bh >> 3;
  const int qt = blockIdx.x;
  const int split = blockIdx.z;
  const int kv0 = split * KPS;
  const int q0 = qt * 64 + w * 16;
  const float* maskb = maskadd + b * SEQL;

  bf16x8 qf[2];
#pragma unroll
  for (int kb = 0; kb < 2; ++kb)
    qf[kb] = *(const bf16x8*)&qg[((size_t)bh * SEQL + q0 + c) * DHH + kb * 32 + g * 8];

  const __bf16 one1 = (__bf16)1.0f;
  const bf16x8 ones = {one1, one1, one1, one1, one1, one1, one1, one1};

  f32x4 o[4] = {};
  f32x4 lones = {};  // row-sums of P via ones-MFMA
  unsigned short* myP = &Ps[w * 1024];

  for (int kt = 0; kt < KPS / 64; ++kt) {
#pragma unroll
    for (int j = 0; j < 2; ++j) {
      int r = w * 16 + j * 8 + (lane >> 3);
      int cl = (lane & 7) ^ (r & 7);
      GLDS16(kg + ((size_t)bh * SEQL + kv0 + kt * 64 + r) * DHH + cl * 8, &Ks[(w * 16 + j * 8) * 64]);
      GLDS16(vtg + ((size_t)bh * DHH + r) * SEQL + kv0 + kt * 64 + cl * 8, &Vts[(w * 16 + j * 8) * 64]);
    }
    __syncthreads();

    // S^T = K @ Q^T + mask (C-init): lane holds S[k = nt*16+g*4+r][q = c], log2 domain
    f32x4 sT[4];
#pragma unroll
    for (int nt = 0; nt < 4; ++nt)
      sT[nt] = *(const f32x4*)&maskb[kv0 + kt * 64 + nt * 16 + g * 4];
#pragma unroll
    for (int nt = 0; nt < 4; ++nt) {
#pragma unroll
      for (int kb = 0; kb < 2; ++kb) {
        int kr = nt * 16 + c;
        int cs = (kb * 4 + g) ^ (kr & 7);
        bf16x8 kf = *(const bf16x8*)&Ks[kr * 64 + cs * 8];
        sT[nt] = __builtin_amdgcn_mfma_f32_16x16x32_bf16(kf, qf[kb], sT[nt], 0, 0, 0);
      }
    }

    // p = exp2(S) (fixed m = 0; masked entries -> exp2(-1e38) = 0), pack, write
#pragma unroll
    for (int nt = 0; nt < 4; ++nt) {
      float pv0 = exp2f(sT[nt][0]), pv1 = exp2f(sT[nt][1]);
      float pv2 = exp2f(sT[nt][2]), pv3 = exp2f(sT[nt][3]);
      unsigned int lo = cvtpk(pv0, pv1), hi = cvtpk(pv2, pv3);
      int off = c * 64 + (((nt * 2 + (g >> 1)) ^ (c & 7)) << 3) + ((g & 1) << 2);
      *(uint2*)(myP + off) = make_uint2(lo, hi);
    }

    // PV + l: A = P, B = Vt (and ones for the row-sum)
#pragma unroll
    for (int kb = 0; kb < 2; ++kb) {
      bf16x8 pf = *(const bf16x8*)&myP[c * 64 + (((kb * 4 + g) ^ (c & 7)) << 3)];
      lones = __builtin_amdgcn_mfma_f32_16x16x32_bf16(pf, ones, lones, 0, 0, 0);
#pragma unroll
      for (int ni = 0; ni < 4; ++ni) {
        int vr = ni * 16 + c;
        int vc = (kb * 4 + g) ^ (vr & 7);
        bf16x8 vf = *(const bf16x8*)&Vts[vr * 64 + vc * 8];
        o[ni] = __builtin_amdgcn_mfma_f32_16x16x32_bf16(pf, vf, o[ni], 0, 0, 0);
      }
    }
    __syncthreads();
  }

  const size_t pb = ((size_t)split * 16 + bh) * SEQL;
#pragma unroll
  for (int ni = 0; ni < 4; ++ni)
#pragma unroll
    for (int r = 0; r < 4; ++r)
      opart[(pb + q0 + g * 4 + r) * DHH + ni * 16 + c] = f2bf(o[ni][r]);
  // lones[r] = l for q-row q0 + g*4 + r (replicated across c); write from c==0 lanes
  if (c == 0) {
#pragma unroll
    for (int r = 0; r < 4; ++r) lpart[pb + q0 + g * 4 + r] = lones[r];
  }
}

__global__ __launch_bounds__(256) void attn_combine(const unsigned short* __restrict__ opart,
                                                    const float* __restrict__ lpart,
                                                    const float* __restrict__ maskadd,
                                                    const float* __restrict__ vmean,
                                                    unsigned short* __restrict__ ctx) {
  int idx = blockIdx.x * 256 + threadIdx.x;  // 16*SEQL*16 threads, 4 d each
  int dq = idx & 15;
  int q = (idx >> 4) & (SEQL - 1);
  int bh = idx >> 15;
  int d0 = dq * 4;
  int b = bh >> 3, h = bh & 7;
  float o0 = 0.f, o1 = 0.f, o2 = 0.f, o3 = 0.f, L = 0.f;
#pragma unroll
  for (int s = 0; s < NSPLIT; ++s) {
    size_t base = ((size_t)s * 16 + bh) * SEQL + q;
    L += lpart[base];
    uint2 v = *(const uint2*)&opart[base * DHH + d0];
    o0 += bf2f(v.x & 0xffff); o1 += bf2f(v.x >> 16);
    o2 += bf2f(v.y & 0xffff); o3 += bf2f(v.y >> 16);
  }
  float r = 1.0f / L;
  o0 *= r; o1 *= r; o2 *= r; o3 *= r;
  if (maskadd[b * SEQL + q] != 0.f) {  // masked q: reference gives uniform attention = mean(V)
    f32x4 vm = *(const f32x4*)&vmean[bh * 64 + d0];
    o0 = vm[0]; o1 = vm[1]; o2 = vm[2]; o3 = vm[3];
  }
  *(uint2*)&ctx[((size_t)(b * SEQL + q)) * INNERD + h * 64 + d0] =
      make_uint2(cvtpk(o0, o1), cvtpk(o2, o3));
}

// ---------------- host ----------------
extern "C" void kernel_launch(void* const* d_in, const int* in_sizes, int n_in,
                              void* d_out, int out_size, void* d_ws, size_t ws_size,
                              hipStream_t stream) {
  (void)in_sizes; (void)n_in; (void)out_size;
  const float* x_in = (const float*)d_in[0];
  const int* mask = (const int*)d_in[1];
  const float* qkv_w = (const float*)d_in[2];
  const float* out_w = (const float*)d_in[3];
  const float* out_b = (const float*)d_in[4];
  const float* ff_w1 = (const float*)d_in[5];
  const float* ff_b1 = (const float*)d_in[6];
  const float* ff_w2 = (const float*)d_in[7];
  const float* ff_b2 = (const float*)d_in[8];
  const float* ad1w = (const float*)d_in[9];
  const float* ad1b = (const float*)d_in[10];
  const float* ad2w = (const float*)d_in[11];
  const float* ad2b = (const float*)d_in[12];

  char* ws = (char*)d_ws;
  size_t off = 0;
  auto alloc = [&](size_t bytes) {
    char* p = ws + off;
    off = (off + bytes + 255) & ~(size_t)255;
    return p;
  };
  unsigned short* wtQ = (unsigned short*)alloc((size_t)DEPTHL * 1536 * 512 * 2);
  unsigned short* wtO = (unsigned short*)alloc((size_t)DEPTHL * 512 * 512 * 2);
  unsigned short* wtF1 = (unsigned short*)alloc((size_t)DEPTHL * 2048 * 512 * 2);
  unsigned short* wtF2 = (unsigned short*)alloc((size_t)DEPTHL * 512 * 2048 * 2);
  float* xc = (float*)alloc((size_t)ROWS * DIMM * 4);
  unsigned short* hbf = (unsigned short*)alloc((size_t)ROWS * DIMM * 2);
  unsigned short* qkvbf = (unsigned short*)alloc((size_t)ROWS * 1536 * 2);
  char* region2 = alloc((size_t)4 * 16 * SEQL * DHH * 2);  // q,k,vt,ctx OR h1
  unsigned short* qb = (unsigned short*)region2;
  unsigned short* kb = qb + (size_t)16 * SEQL * DHH;
  unsigned short* vtb = kb + (size_t)16 * SEQL * DHH;
  unsigned short* ctxb = vtb + (size_t)16 * SEQL * DHH;
  unsigned short* h1bf = (unsigned short*)region2;  // aliases q/k/vt/ctx (disjoint lifetime)
  float* p1 = (float*)alloc((size_t)BB * 32 * DIMM * 4);
  float* p2 = (float*)alloc((size_t)BB * 32 * DIMM * 4);
  float* alpha = (float*)alloc((size_t)BB * DIMM * 4);
  float* beta = (float*)alloc((size_t)BB * DIMM * 4);
  float* maskadd = (float*)alloc((size_t)BB * SEQL * 4);
  unsigned short* opart = (unsigned short*)alloc((size_t)NSPLIT * 16 * SEQL * DHH * 2);
  float* lpart = (float*)alloc((size_t)NSPLIT * 16 * SEQL * 4);
  float* vmean = (float*)alloc((size_t)16 * 64 * 4);
  unsigned short* part = (unsigned short*)alloc((size_t)4 * ROWS * 512 * 2);  // 16MB bf16 split-K partials
  const bool fits = off <= ws_size;  // graceful fallback if workspace too small

  // x working copy
  hipMemcpyAsync(xc, x_in, (size_t)ROWS * DIMM * 4, hipMemcpyDeviceToDevice, stream);

  // weights -> bf16 transposed [N][K]
  wtrans<<<dim3(512 / 32, 1536 / 32, DEPTHL), 256, 0, stream>>>(qkv_w, wtQ, 512, 1536);
  wtrans<<<dim3(512 / 32, 512 / 32, DEPTHL), 256, 0, stream>>>(out_w, wtO, 512, 512);
  wtrans<<<dim3(512 / 32, 2048 / 32, DEPTHL), 256, 0, stream>>>(ff_w1, wtF1, 512, 2048);
  wtrans<<<dim3(2048 / 32, 512 / 32, DEPTHL), 256, 0, stream>>>(ff_w2, wtF2, 2048, 512);
  maskbuild<<<BB * SEQL / 256, 256, 0, stream>>>(mask, maskadd);

  for (int l = 0; l < DEPTHL; ++l) {
    // adain 1
    adain_p1<<<dim3(32, BB), 512, 0, stream>>>(xc, p1, p2);
    adain_p2<<<BB, 512, 0, stream>>>(p1, p2, ad1w + l * BB * DIMM, ad1b + l * BB * DIMM, alpha, beta);
    adain_apply<<<8192, 256, 0, stream>>>(xc, alpha, beta, hbf);
    // qkv: [4096,512] x [512,1536] -> bf16
    gemm_k<0, 64><<<dim3(1536 / 64, ROWS / 128), 256, 0, stream>>>(
        hbf, wtQ + (size_t)l * 1536 * 512, nullptr, nullptr, nullptr, qkvbf, nullptr, 1536, 512);
    repack_qk<<<8192, 256, 0, stream>>>(qkvbf, qb, kb);
    transpose_v<<<dim3(16, 32), 256, 0, stream>>>(qkvbf, vtb);
    vmean_k<<<dim3(16, 8), 256, 0, stream>>>(vtb, vmean);
    attn_split<<<dim3(SEQL / 64, 16, NSPLIT), 256, 0, stream>>>(qb, kb, vtb, maskadd, opart, lpart);
    attn_combine<<<16 * SEQL * 16 / 256, 256, 0, stream>>>(opart, lpart, maskadd, vmean, ctxb);
    // out proj + residual (in place on xc)
    if (fits) {
      gemm_k<3, 64><<<dim3(512 / 64, ROWS / 128, 2), 256, 0, stream>>>(
          ctxb, wtO + (size_t)l * 512 * 512, nullptr, nullptr, nullptr, nullptr, part, 512, 512);
      comb_k<2><<<ROWS * 512 / 1024, 256, 0, stream>>>(part, out_b + l * DIMM, xc, xc);
    } else {
      gemm_k<2, 64><<<dim3(512 / 64, ROWS / 128), 256, 0, stream>>>(
          ctxb, wtO + (size_t)l * 512 * 512, out_b + l * DIMM, xc, xc, nullptr, nullptr, 512, 512);
    }
    // adain 2
    adain_p1<<<dim3(32, BB), 512, 0, stream>>>(xc, p1, p2);
    adain_p2<<<BB, 512, 0, stream>>>(p1, p2, ad2w + l * BB * DIMM, ad2b + l * BB * DIMM, alpha, beta);
    adain_apply<<<8192, 256, 0, stream>>>(xc, alpha, beta, hbf);
    // ff1 (gelu) -> h1
    gemm_k<1, 64><<<dim3(2048 / 64, ROWS / 128), 256, 0, stream>>>(
        hbf, wtF1 + (size_t)l * 2048 * 512, ff_b1 + l * MLPD, nullptr, nullptr, h1bf, nullptr, 2048, 512);
    // ff2 + residual
    float* xout = (l == DEPTHL - 1) ? (float*)d_out : xc;
    if (fits) {
      gemm_k<3, 64><<<dim3(512 / 64, ROWS / 128, 4), 256, 0, stream>>>(
          h1bf, wtF2 + (size_t)l * 512 * 2048, nullptr, nullptr, nullptr, nullptr, part, 512, 2048);
      comb_k<4><<<ROWS * 512 / 1024, 256, 0, stream>>>(part, ff_b2 + l * DIMM, xc, xout);
    } else {
      gemm_k<2, 64><<<dim3(512 / 64, ROWS / 128), 256, 0, stream>>>(
          h1bf, wtF2 + (size_t)l * 512 * 2048, ff_b2 + l * DIMM, xc, xout, nullptr, nullptr, 512, 2048);
    }
  }
}